// Round 10
// baseline (70.889 us; speedup 1.0000x reference)
//
#include <hip/hip_runtime.h>
#include <math.h>

#define NP 65536
#define NJ 16
#define WID 64
#define HH 64
#define NPOU 4
#define NSUB 2
#define L2E2 2.8853900817779268f   // 2*log2(e)

typedef __attribute__((ext_vector_type(8))) short short8;
typedef __attribute__((ext_vector_type(4))) float f32x4;
typedef __attribute__((ext_vector_type(4))) int int4v;

// swizzled LDS layout (fallback kernels only)
#define CHUNK_US(row, chunk) ((((row) << 6)) + ((((chunk) ^ ((row) & 7))) << 3))
__device__ __forceinline__ int usIdx(int row, int col) {
    return ((row) << 6) + ((((col >> 3) ^ (row & 7))) << 3) + (col & 7);
}

__device__ __forceinline__ unsigned short f2bf(float f) {   // RNE
    unsigned u = __float_as_uint(f);
    u += 0x7FFFu + ((u >> 16) & 1u);
    return (unsigned short)(u >> 16);
}
__device__ __forceinline__ unsigned short rhu(float f) {
    return (unsigned short)((__float_as_uint(f) + 0x8000u) >> 16);
}
__device__ __forceinline__ unsigned pk2(float a, float b) {
    unsigned ua = __float_as_uint(a) + 0x8000u;
    unsigned ub = __float_as_uint(b) + 0x8000u;
    return __builtin_amdgcn_perm(ub, ua, 0x07060302u);
}
__device__ __forceinline__ unsigned cvtpk(float a, float b) { // HW pack, RNE
    unsigned r;
    asm("v_cvt_pk_bf16_f32 %0, %1, %2" : "=v"(r) : "v"(a), "v"(b));
    return r;
}
__device__ __forceinline__ float bf2f(unsigned short s) {
    return __uint_as_float(((unsigned)s) << 16);
}
// tanh with argument pre-scaled by 2*log2e: tanh(z) = 1 - 2/(2^y+1)
__device__ __forceinline__ float tanh2(float y) {
    float e = __builtin_amdgcn_exp2f(y);
    return fmaf(-2.0f, __builtin_amdgcn_rcpf(e + 1.0f), 1.0f);
}
__device__ __forceinline__ short8 mk8(unsigned a, unsigned b, unsigned c, unsigned d) {
    int4v t; t.x = (int)a; t.y = (int)b; t.z = (int)c; t.w = (int)d;
    return __builtin_bit_cast(short8, t);
}
// C-layout (16 rows {..+4g+q} x col) -> B-frag (k=kn*32+8g+e) pair transform
#define CB_TRANSFORM(hsrc, bfdst)                                              \
    {                                                                          \
        _Pragma("unroll")                                                      \
        for (int kn = 0; kn < 2; ++kn) {                                       \
            unsigned A0 = cvtpk(hsrc[2 * kn][0],     hsrc[2 * kn][1]);         \
            unsigned A1 = cvtpk(hsrc[2 * kn][2],     hsrc[2 * kn][3]);         \
            unsigned B0 = cvtpk(hsrc[2 * kn + 1][0], hsrc[2 * kn + 1][1]);     \
            unsigned B1 = cvtpk(hsrc[2 * kn + 1][2], hsrc[2 * kn + 1][3]);     \
            asm("v_permlane32_swap_b32 %0, %1" : "+v"(A0), "+v"(B0));          \
            asm("v_permlane16_swap_b32 %0, %1" : "+v"(A0), "+v"(B0));          \
            asm("v_permlane32_swap_b32 %0, %1" : "+v"(A1), "+v"(B1));          \
            asm("v_permlane16_swap_b32 %0, %1" : "+v"(A1), "+v"(B1));          \
            bfdst[kn] = mk8(A0, A1, B0, B1);                                   \
        }                                                                      \
    }

// ============== Merged prep: blocks [0,64) = subnet frags/params, [64,73) = pou ==============
__global__ __launch_bounds__(256) void prep_all_kernel(
    const float* __restrict__ sW0, const float* __restrict__ sb0,
    const float* __restrict__ sWh, const float* __restrict__ sbh_,
    const float* __restrict__ sWl, const float* __restrict__ sbl,
    const float* __restrict__ pW0, const float* __restrict__ pb0,
    const float* __restrict__ pWh, const float* __restrict__ pbh,
    const float* __restrict__ pWl, const float* __restrict__ pbl,
    int4v* __restrict__ wfrag, float* __restrict__ prm,
    int4v* __restrict__ pwf,   float* __restrict__ pp)
{
    const int blk = blockIdx.x;
    const int tid = threadIdx.x;

    if (blk < 64) {
        // ---------------- subnet prep ----------------
        const int j  = blk >> 2;
        const int bx = blk & 3;
        const int f  = bx * 256 + tid;
        const int lane = f & 63, kc = (f >> 6) & 1, mt = (f >> 7) & 3, L = f >> 9;
        const int c = lane & 15, g = lane >> 4;
        const int n = mt * 16 + c;

        const float* src = sWh + j * (NSUB * WID * WID) + L * 4096;
        unsigned w[4];
#pragma unroll
        for (int e2 = 0; e2 < 4; ++e2) {
            int k = kc * 32 + 8 * g + 2 * e2;
            float v0 = L2E2 * src[k * 64 + n];
            float v1 = L2E2 * src[(k + 1) * 64 + n];
            w[e2] = (unsigned)f2bf(v0) | ((unsigned)f2bf(v1) << 16);
        }
        int4v r; r.x = (int)w[0]; r.y = (int)w[1]; r.z = (int)w[2]; r.w = (int)w[3];
        wfrag[j * 1024 + f] = r;

        if (bx == 0) {
            float* pj = prm + j * 512;
            if (tid < WID) {
                float w0 = sW0[j * 2 * WID + tid], w1 = sW0[j * 2 * WID + WID + tid];
                pj[tid]       = 2.0f * L2E2 * w0;
                pj[64 + tid]  = 2.0f * L2E2 * w1;
                pj[128 + tid] = L2E2 * (sb0[j * WID + tid] - w0 - w1);
            }
            if (tid < NSUB * WID) pj[192 + tid] = L2E2 * sbh_[j * NSUB * WID + tid];
            if (tid < WID) pj[320 + tid] = sWl[j * WID + tid];
            if (tid == 0) pj[384] = sbl[j];
        }
    } else {
        // ---------------- pou prep ----------------
        const int pb = blk - 64;
        const int idx = pb * 256 + tid;

        if (idx < 2048) {
            const int r = idx >> 9, mt = (idx >> 7) & 3, kc = (idx >> 6) & 1, lane = idx & 63;
            const int c = lane & 15, g = lane >> 4;
            const int n = mt * 16 + c;
            const float* src = pWh + r * 4096;
            unsigned w[4];
#pragma unroll
            for (int e2 = 0; e2 < 4; ++e2) {
                int k = kc * 32 + 8 * g + 2 * e2;
                w[e2] = (unsigned)f2bf(src[k * 64 + n]) | ((unsigned)f2bf(src[(k + 1) * 64 + n]) << 16);
            }
            int4v rr; rr.x = (int)w[0]; rr.y = (int)w[1]; rr.z = (int)w[2]; rr.w = (int)w[3];
            pwf[idx] = rr;
        } else if (idx < 2176) {
            const int t = idx - 2048;
            const int kc = t >> 6, lane = t & 63;
            const int jj = lane & 15, g = lane >> 4;
            unsigned w[4];
#pragma unroll
            for (int e2 = 0; e2 < 4; ++e2) {
                int k = kc * 32 + 8 * g + 2 * e2;
                w[e2] = (unsigned)f2bf(pWl[k * 16 + jj]) | ((unsigned)f2bf(pWl[(k + 1) * 16 + jj]) << 16);
            }
            int4v rr; rr.x = (int)w[0]; rr.y = (int)w[1]; rr.z = (int)w[2]; rr.w = (int)w[3];
            pwf[idx] = rr;
        }
        if (pb == 8) {   // pou param block
            if (tid < HH) {
                pp[tid]       = pW0[tid];
                pp[64 + tid]  = pW0[HH + tid];
                pp[128 + tid] = pb0[tid];
            }
            pp[192 + tid] = pbh[tid];          // 256 entries
            if (tid < NJ) pp[448 + tid] = pbl[tid];
        }
    }
}

// ============ POU, 16 pts/wave, no LDS (R8/R9-proven) ============
__global__ __launch_bounds__(256) void pou16_kernel(
    const float* __restrict__ x,
    const short8* __restrict__ pwf, const float* __restrict__ pp,
    float* __restrict__ w_all)
{
    const int tid = threadIdx.x, wave = tid >> 6, lane = tid & 63;
    const int c = lane & 15, g = lane >> 4;
    const int pb = blockIdx.x * 64 + wave * 16;

    float2 xv = ((const float2*)x)[pb + c];

    float trunk[4][4];
#pragma unroll
    for (int mt = 0; mt < 4; ++mt) {
        f32x4 a  = *(const f32x4*)&pp[      mt * 16 + 4 * g];
        f32x4 b  = *(const f32x4*)&pp[ 64 + mt * 16 + 4 * g];
        f32x4 bb = *(const f32x4*)&pp[128 + mt * 16 + 4 * g];
#pragma unroll
        for (int q = 0; q < 4; ++q)
            trunk[mt][q] = fmaxf(fmaf(xv.x, a[q], fmaf(xv.y, b[q], bb[q])), 0.0f);
    }

#pragma unroll
    for (int r = 0; r < NPOU; ++r) {
        short8 bf[2];
        CB_TRANSFORM(trunk, bf);
        f32x4 acc[4];
#pragma unroll
        for (int mt = 0; mt < 4; ++mt)
            acc[mt] = *(const f32x4*)&pp[192 + r * 64 + mt * 16 + 4 * g];
#pragma unroll
        for (int mt = 0; mt < 4; ++mt) {
            short8 a0 = pwf[((r * 4 + mt) * 2 + 0) * 64 + lane];
            short8 a1 = pwf[((r * 4 + mt) * 2 + 1) * 64 + lane];
            acc[mt] = __builtin_amdgcn_mfma_f32_16x16x32_bf16(a0, bf[0], acc[mt], 0, 0, 0);
            acc[mt] = __builtin_amdgcn_mfma_f32_16x16x32_bf16(a1, bf[1], acc[mt], 0, 0, 0);
        }
#pragma unroll
        for (int mt = 0; mt < 4; ++mt)
#pragma unroll
            for (int q = 0; q < 4; ++q)
                trunk[mt][q] += fmaxf(acc[mt][q], 0.0f);
    }

    short8 bfl[2];
    CB_TRANSFORM(trunk, bfl);
    f32x4 lac = *(const f32x4*)&pp[448 + 4 * g];
    lac = __builtin_amdgcn_mfma_f32_16x16x32_bf16(pwf[2048 + lane],      bfl[0], lac, 0, 0, 0);
    lac = __builtin_amdgcn_mfma_f32_16x16x32_bf16(pwf[2048 + 64 + lane], bfl[1], lac, 0, 0, 0);

    float m = fmaxf(fmaxf(lac[0], lac[1]), fmaxf(lac[2], lac[3]));
    m = fmaxf(m, __shfl_xor(m, 16));
    m = fmaxf(m, __shfl_xor(m, 32));
    float ev[4]; float s = 0.0f;
#pragma unroll
    for (int q = 0; q < 4; ++q) { ev[q] = __expf(lac[q] - m); s += ev[q]; }
    s += __shfl_xor(s, 16);
    s += __shfl_xor(s, 32);
    const float rinv = __builtin_amdgcn_rcpf(s);
#pragma unroll
    for (int q = 0; q < 4; ++q)
        w_all[(4 * g + q) * NP + pb + c] = ev[q] * rinv;
}

// ======== Subnet, 64 pts/wave, no LDS (R7/R9-proven; only change: w_all hoisted) ========
__global__ __launch_bounds__(256, 4) void subnet_nolds_kernel(
    const float* __restrict__ x,
    const short8* __restrict__ wfrag,
    const float* __restrict__ prm,
    const float* __restrict__ w_all,
    float* __restrict__ upart)
{
    const int tid  = threadIdx.x;
    const int j    = blockIdx.y;
    const int wave = tid >> 6;
    const int lane = tid & 63;
    const int c    = lane & 15;
    const int g    = lane >> 4;

    const float*  pj = prm + j * 512;
    const short8* wf = wfrag + j * 1024;
    const int pb = blockIdx.x * 256 + wave * 64;

    // hoisted: w_all read issues now, completes under the network evaluation
    const float wv = w_all[j * NP + pb + lane];

    // ---- L0 directly in B-frag layout ----
    short8 bf[2][4];
    {
        float xs0[4], xs1[4];
#pragma unroll
        for (int nt = 0; nt < 4; ++nt) {
            float2 xv = ((const float2*)x)[pb + nt * 16 + c];
            xs0[nt] = xv.x; xs1[nt] = xv.y;
        }
        f32x4 wa[2][2], wb[2][2], bb[2][2];
#pragma unroll
        for (int kc = 0; kc < 2; ++kc)
#pragma unroll
            for (int hf = 0; hf < 2; ++hf) {
                wa[kc][hf] = *(const f32x4*)&pj[      kc * 32 + 8 * g + 4 * hf];
                wb[kc][hf] = *(const f32x4*)&pj[ 64 + kc * 32 + 8 * g + 4 * hf];
                bb[kc][hf] = *(const f32x4*)&pj[128 + kc * 32 + 8 * g + 4 * hf];
            }
        unsigned t[2][4][4];
#pragma unroll
        for (int kc = 0; kc < 2; ++kc)
#pragma unroll
            for (int pr = 0; pr < 4; ++pr) {
                const int h0 = pr >> 1, e0 = (2 * pr) & 3, e1 = e0 + 1;
#pragma unroll
                for (int nt = 0; nt < 4; ++nt) {
                    float v0 = tanh2(fmaf(xs0[nt], wa[kc][h0][e0], fmaf(xs1[nt], wb[kc][h0][e0], bb[kc][h0][e0])));
                    float v1 = tanh2(fmaf(xs0[nt], wa[kc][h0][e1], fmaf(xs1[nt], wb[kc][h0][e1], bb[kc][h0][e1])));
                    t[kc][nt][pr] = cvtpk(v0, v1);
                }
            }
#pragma unroll
        for (int kc = 0; kc < 2; ++kc)
#pragma unroll
            for (int nt = 0; nt < 4; ++nt)
                bf[kc][nt] = mk8(t[kc][nt][0], t[kc][nt][1], t[kc][nt][2], t[kc][nt][3]);
    }

    float red[4];
#pragma unroll
    for (int nt = 0; nt < 4; ++nt) red[nt] = 0.0f;

    // ---- hidden layers: A-frags straight from global (L2-resident) ----
#pragma unroll
    for (int L = 0; L < NSUB; ++L) {
        short8 aw[4][2];
#pragma unroll
        for (int mt = 0; mt < 4; ++mt)
#pragma unroll
            for (int kc = 0; kc < 2; ++kc)
                aw[mt][kc] = wf[((L * 4 + mt) * 2 + kc) * 64 + lane];
        f32x4 bias[4];
#pragma unroll
        for (int mt = 0; mt < 4; ++mt)
            bias[mt] = *(const f32x4*)&pj[192 + L * 64 + mt * 16 + 4 * g];

#pragma unroll
        for (int nt = 0; nt < 4; ++nt) {
            f32x4 acc[4];
#pragma unroll
            for (int mt = 0; mt < 4; ++mt) acc[mt] = bias[mt];
#pragma unroll
            for (int mt = 0; mt < 4; ++mt) {
                acc[mt] = __builtin_amdgcn_mfma_f32_16x16x32_bf16(aw[mt][0], bf[0][nt], acc[mt], 0, 0, 0);
                acc[mt] = __builtin_amdgcn_mfma_f32_16x16x32_bf16(aw[mt][1], bf[1][nt], acc[mt], 0, 0, 0);
            }

            if (L < NSUB - 1) {
                float h[4][4];
#pragma unroll
                for (int mt = 0; mt < 4; ++mt)
#pragma unroll
                    for (int q = 0; q < 4; ++q) h[mt][q] = tanh2(acc[mt][q]);
                short8 btmp[2];
                CB_TRANSFORM(h, btmp);
                bf[0][nt] = btmp[0];
                bf[1][nt] = btmp[1];
            } else {
#pragma unroll
                for (int mt = 0; mt < 4; ++mt) {
                    f32x4 wlv = *(const f32x4*)&pj[320 + mt * 16 + 4 * g];
#pragma unroll
                    for (int q = 0; q < 4; ++q)
                        red[nt] = fmaf(tanh2(acc[mt][q]), wlv[q], red[nt]);
                }
            }
        }
    }

#pragma unroll
    for (int nt = 0; nt < 4; ++nt) {
        red[nt] += __shfl_xor(red[nt], 16);
        red[nt] += __shfl_xor(red[nt], 32);
    }
    float u = (g & 1) ? ((g & 2) ? red[3] : red[1]) : ((g & 2) ? red[2] : red[0]);
    u += pj[384];

    const int p = pb + lane;
    upart[j * NP + p] = u * wv;
}

// ================= Fallback kernels (ws-guard path; proven structure) =========
__global__ __launch_bounds__(256) void pou_mfma_kernel(
    const float* __restrict__ x,
    const float* __restrict__ W0, const float* __restrict__ b0,
    const float* __restrict__ Wh, const float* __restrict__ bh,
    const float* __restrict__ Wl, const float* __restrict__ bl,
    float* __restrict__ w_all)
{
    __shared__ unsigned short sA[4 * 64 * 64];
    __shared__ unsigned short sWhT[NPOU * 64 * 64];
    __shared__ unsigned short sWlT[16 * 64];
    __shared__ float sW0a[HH], sW0b[HH], sB0[HH];
    __shared__ float sbh[NPOU * HH];
    __shared__ float sbl[NJ];

    const int tid  = threadIdx.x;
    const int wave = tid >> 6;
    const int lane = tid & 63;
    const int r15  = lane & 15;
    const int g    = lane >> 4;

    for (int idx = tid; idx < NPOU * HH * HH; idx += 256) {
        int r = idx >> 12, k = (idx >> 6) & 63, n = idx & 63;
        sWhT[r * 4096 + usIdx(n, k)] = f2bf(Wh[idx]);
    }
    for (int idx = tid; idx < HH * NJ; idx += 256) {
        int k = idx >> 4, j = idx & 15;
        sWlT[usIdx(j, k)] = f2bf(Wl[idx]);
    }
    if (tid < HH) { sW0a[tid] = W0[tid]; sW0b[tid] = W0[HH + tid]; sB0[tid] = b0[tid]; }
    for (int i = tid; i < NPOU * HH; i += 256) sbh[i] = bh[i];
    if (tid < NJ) sbl[tid] = bl[tid];
    __syncthreads();

    unsigned short* myA = &sA[wave * 4096];
    const int pbase = blockIdx.x * 256;

    {
        const int p = pbase + tid;
        float2 xv = ((const float2*)x)[p];
        float v[HH];
#pragma unroll
        for (int c = 0; c < HH; ++c)
            v[c] = fmaxf(fmaf(xv.x, sW0a[c], fmaf(xv.y, sW0b[c], sB0[c])), 0.0f);
#pragma unroll
        for (int c = 0; c < 8; ++c) {
            int4v r;
            r.x = (int)pk2(v[8 * c + 0], v[8 * c + 1]);
            r.y = (int)pk2(v[8 * c + 2], v[8 * c + 3]);
            r.z = (int)pk2(v[8 * c + 4], v[8 * c + 5]);
            r.w = (int)pk2(v[8 * c + 6], v[8 * c + 7]);
            *(int4v*)&myA[CHUNK_US(lane, c)] = r;
        }
    }

    float trunk[4][4][4];
#pragma unroll
    for (int mt = 0; mt < 4; ++mt)
#pragma unroll
        for (int nt = 0; nt < 4; ++nt)
#pragma unroll
            for (int q = 0; q < 4; ++q)
                trunk[mt][nt][q] = bf2f(myA[usIdx(mt * 16 + g * 4 + q, nt * 16 + r15)]);

#pragma unroll 1
    for (int r = 0; r < NPOU; ++r) {
        const unsigned short* wt = &sWhT[r * 4096];
        short8 bfr[2][4];
#pragma unroll
        for (int kc = 0; kc < 2; ++kc)
#pragma unroll
            for (int nt = 0; nt < 4; ++nt)
                bfr[kc][nt] = *(const short8*)&wt[CHUNK_US(nt * 16 + r15, kc * 4 + g)];
        float bias[4];
#pragma unroll
        for (int nt = 0; nt < 4; ++nt) bias[nt] = sbh[r * HH + nt * 16 + r15];

#pragma unroll
        for (int mt = 0; mt < 4; ++mt) {
            short8 a0 = *(const short8*)&myA[CHUNK_US(mt * 16 + r15, g)];
            short8 a1 = *(const short8*)&myA[CHUNK_US(mt * 16 + r15, 4 + g)];
            f32x4 acc[4];
#pragma unroll
            for (int nt = 0; nt < 4; ++nt) {
                acc[nt] = (f32x4)(0.0f);
                acc[nt] = __builtin_amdgcn_mfma_f32_16x16x32_bf16(a0, bfr[0][nt], acc[nt], 0, 0, 0);
                acc[nt] = __builtin_amdgcn_mfma_f32_16x16x32_bf16(a1, bfr[1][nt], acc[nt], 0, 0, 0);
            }
#pragma unroll
            for (int nt = 0; nt < 4; ++nt)
#pragma unroll
                for (int q = 0; q < 4; ++q) {
                    float t = trunk[mt][nt][q] + fmaxf(acc[nt][q] + bias[nt], 0.0f);
                    trunk[mt][nt][q] = t;
                    myA[usIdx(mt * 16 + g * 4 + q, nt * 16 + r15)] = rhu(t);
                }
        }
    }

    short8 bw0 = *(const short8*)&sWlT[CHUNK_US(r15, g)];
    short8 bw1 = *(const short8*)&sWlT[CHUNK_US(r15, 4 + g)];
    float lg[4][4], mx[4][4];
#pragma unroll
    for (int mt = 0; mt < 4; ++mt) {
        short8 a0 = *(const short8*)&myA[CHUNK_US(mt * 16 + r15, g)];
        short8 a1 = *(const short8*)&myA[CHUNK_US(mt * 16 + r15, 4 + g)];
        f32x4 acc = (f32x4)(0.0f);
        acc = __builtin_amdgcn_mfma_f32_16x16x32_bf16(a0, bw0, acc, 0, 0, 0);
        acc = __builtin_amdgcn_mfma_f32_16x16x32_bf16(a1, bw1, acc, 0, 0, 0);
#pragma unroll
        for (int q = 0; q < 4; ++q) { lg[mt][q] = acc[q] + sbl[r15]; mx[mt][q] = lg[mt][q]; }
    }
#pragma unroll
    for (int mask = 1; mask < 16; mask <<= 1)
#pragma unroll
        for (int mt = 0; mt < 4; ++mt)
#pragma unroll
            for (int q = 0; q < 4; ++q) mx[mt][q] = fmaxf(mx[mt][q], __shfl_xor(mx[mt][q], mask));
    float ev[4][4], sm[4][4];
#pragma unroll
    for (int mt = 0; mt < 4; ++mt)
#pragma unroll
        for (int q = 0; q < 4; ++q) { ev[mt][q] = __expf(lg[mt][q] - mx[mt][q]); sm[mt][q] = ev[mt][q]; }
#pragma unroll
    for (int mask = 1; mask < 16; mask <<= 1)
#pragma unroll
        for (int mt = 0; mt < 4; ++mt)
#pragma unroll
            for (int q = 0; q < 4; ++q) sm[mt][q] += __shfl_xor(sm[mt][q], mask);
#pragma unroll
    for (int mt = 0; mt < 4; ++mt)
#pragma unroll
        for (int q = 0; q < 4; ++q) {
            const int p = pbase + wave * 64 + mt * 16 + g * 4 + q;
            w_all[r15 * NP + p] = ev[mt][q] * __builtin_amdgcn_rcpf(sm[mt][q]);
        }
}

__global__ __launch_bounds__(256) void subnet_mfma_fallback(
    const float* __restrict__ x,
    const float* __restrict__ gW0, const float* __restrict__ gb0,
    const float* __restrict__ gWh, const float* __restrict__ gbh,
    const float* __restrict__ gWl, const float* __restrict__ gbl,
    const float* __restrict__ w_all,
    float* __restrict__ upart)
{
    __shared__ __align__(16) unsigned short sWt[NSUB * 64 * 64];
    __shared__ __align__(16) float sW0a[WID], sW0b[WID], sB0[WID];
    __shared__ __align__(16) float sbh[NSUB * WID];
    __shared__ __align__(16) float sWl[WID];
    __shared__ float sbl1v;

    const int tid  = threadIdx.x;
    const int j    = blockIdx.y;
    const int wave = tid >> 6;
    const int lane = tid & 63;
    const int c    = lane & 15;
    const int g    = lane >> 4;

    {
        const float* src = gWh + j * (NSUB * WID * WID);
        for (int idx = tid; idx < NSUB * WID * WID; idx += 256) {
            int L = idx >> 12, rem = idx & 4095;
            int k = rem >> 6, n = rem & 63;
            sWt[L * 4096 + usIdx(n, k)] = f2bf(L2E2 * src[idx]);
        }
        if (tid < WID) {
            float w0 = gW0[j * 2 * WID + tid], w1 = gW0[j * 2 * WID + WID + tid];
            sW0a[tid] = 2.0f * L2E2 * w0;
            sW0b[tid] = 2.0f * L2E2 * w1;
            sB0[tid]  = L2E2 * (gb0[j * WID + tid] - w0 - w1);
        }
        if (tid < NSUB * WID) sbh[tid] = L2E2 * gbh[j * NSUB * WID + tid];
        if (tid < WID) sWl[tid] = gWl[j * WID + tid];
        if (tid == 0) sbl1v = gbl[j];
    }
    __syncthreads();

    const int pb = blockIdx.x * 256 + wave * 64;

    short8 bf[2][4];
    {
        float xs0[4], xs1[4];
#pragma unroll
        for (int nt = 0; nt < 4; ++nt) {
            float2 xv = ((const float2*)x)[pb + nt * 16 + c];
            xs0[nt] = xv.x; xs1[nt] = xv.y;
        }
        f32x4 wa[2][2], wb[2][2], bb[2][2];
#pragma unroll
        for (int kc = 0; kc < 2; ++kc)
#pragma unroll
            for (int hf = 0; hf < 2; ++hf) {
                wa[kc][hf] = *(const f32x4*)&sW0a[kc * 32 + 8 * g + 4 * hf];
                wb[kc][hf] = *(const f32x4*)&sW0b[kc * 32 + 8 * g + 4 * hf];
                bb[kc][hf] = *(const f32x4*)&sB0 [kc * 32 + 8 * g + 4 * hf];
            }
        unsigned t[2][4][4];
#pragma unroll
        for (int kc = 0; kc < 2; ++kc)
#pragma unroll
            for (int pr = 0; pr < 4; ++pr) {
                const int h0 = pr >> 1, e0 = (2 * pr) & 3, e1 = e0 + 1;
#pragma unroll
                for (int nt = 0; nt < 4; ++nt) {
                    float v0 = tanh2(fmaf(xs0[nt], wa[kc][h0][e0], fmaf(xs1[nt], wb[kc][h0][e0], bb[kc][h0][e0])));
                    float v1 = tanh2(fmaf(xs0[nt], wa[kc][h0][e1], fmaf(xs1[nt], wb[kc][h0][e1], bb[kc][h0][e1])));
                    t[kc][nt][pr] = cvtpk(v0, v1);
                }
            }
#pragma unroll
        for (int kc = 0; kc < 2; ++kc)
#pragma unroll
            for (int nt = 0; nt < 4; ++nt)
                bf[kc][nt] = mk8(t[kc][nt][0], t[kc][nt][1], t[kc][nt][2], t[kc][nt][3]);
    }

    float red[4];
#pragma unroll
    for (int nt = 0; nt < 4; ++nt) red[nt] = 0.0f;

#pragma unroll
    for (int L = 0; L < NSUB; ++L) {
        const unsigned short* wt = &sWt[L * 4096];
        short8 aw[4][2];
#pragma unroll
        for (int mt = 0; mt < 4; ++mt)
#pragma unroll
            for (int kc = 0; kc < 2; ++kc)
                aw[mt][kc] = *(const short8*)&wt[CHUNK_US(mt * 16 + c, kc * 4 + g)];
        f32x4 bias[4];
#pragma unroll
        for (int mt = 0; mt < 4; ++mt)
            bias[mt] = *(const f32x4*)&sbh[L * 64 + mt * 16 + 4 * g];

#pragma unroll
        for (int nt = 0; nt < 4; ++nt) {
            f32x4 acc[4];
#pragma unroll
            for (int mt = 0; mt < 4; ++mt) acc[mt] = bias[mt];
#pragma unroll
            for (int mt = 0; mt < 4; ++mt) {
                acc[mt] = __builtin_amdgcn_mfma_f32_16x16x32_bf16(aw[mt][0], bf[0][nt], acc[mt], 0, 0, 0);
                acc[mt] = __builtin_amdgcn_mfma_f32_16x16x32_bf16(aw[mt][1], bf[1][nt], acc[mt], 0, 0, 0);
            }

            if (L < NSUB - 1) {
                float h[4][4];
#pragma unroll
                for (int mt = 0; mt < 4; ++mt)
#pragma unroll
                    for (int q = 0; q < 4; ++q) h[mt][q] = tanh2(acc[mt][q]);
                short8 btmp[2];
                CB_TRANSFORM(h, btmp);
                bf[0][nt] = btmp[0];
                bf[1][nt] = btmp[1];
            } else {
#pragma unroll
                for (int mt = 0; mt < 4; ++mt) {
                    f32x4 wlv = *(const f32x4*)&sWl[mt * 16 + 4 * g];
#pragma unroll
                    for (int q = 0; q < 4; ++q)
                        red[nt] = fmaf(tanh2(acc[mt][q]), wlv[q], red[nt]);
                }
            }
        }
    }

#pragma unroll
    for (int nt = 0; nt < 4; ++nt) {
        red[nt] += __shfl_xor(red[nt], 16);
        red[nt] += __shfl_xor(red[nt], 32);
    }
    float u = (g & 1) ? ((g & 2) ? red[3] : red[1]) : ((g & 2) ? red[2] : red[0]);
    u += sbl1v;

    const int p = pb + lane;
    upart[j * NP + p] = u * w_all[j * NP + p];
}

// ============ Reduce over j + Dirichlet ansatz (scalar/thread, 256 blocks) ============
__global__ __launch_bounds__(256) void reduce_kernel(
    const float* __restrict__ x,
    const float* __restrict__ upart,
    float* __restrict__ out)
{
    const int p = blockIdx.x * 256 + threadIdx.x;
    float s = 0.0f;
#pragma unroll
    for (int j = 0; j < NJ; ++j) s += upart[j * NP + p];
    float2 xv = ((const float2*)x)[p];
    float s0 = __builtin_amdgcn_sinf(xv.x * 0.5f);
    float s1 = __builtin_amdgcn_sinf(xv.y * 0.5f);
    out[p] = s * s0 * s1;
}

extern "C" void kernel_launch(void* const* d_in, const int* in_sizes, int n_in,
                              void* d_out, int out_size, void* d_ws, size_t ws_size,
                              hipStream_t stream) {
    const float* x      = (const float*)d_in[0];
    const float* sub_W0 = (const float*)d_in[1];
    const float* sub_b0 = (const float*)d_in[2];
    const float* sub_Wh = (const float*)d_in[3];
    const float* sub_bh = (const float*)d_in[4];
    const float* sub_Wl = (const float*)d_in[5];
    const float* sub_bl = (const float*)d_in[6];
    const float* pou_W0 = (const float*)d_in[7];
    const float* pou_b0 = (const float*)d_in[8];
    const float* pou_Wh = (const float*)d_in[9];
    const float* pou_bh = (const float*)d_in[10];
    const float* pou_Wl = (const float*)d_in[11];
    const float* pou_bl = (const float*)d_in[12];

    float* w_all = (float*)d_ws;                   // [J][P] 4 MB
    float* upart = (float*)d_ws + (size_t)NJ * NP; // [J][P] 4 MB
    char*  extra  = (char*)d_ws + (size_t)2 * NJ * NP * 4;
    void*  swf    = (void*)extra;                               // 256 KB subnet frags
    float* sprm   = (float*)(extra + (size_t)NJ * 1024 * 16);   // 32 KB subnet params
    char*  extra2 = extra + (size_t)NJ * 1024 * 16 + (size_t)NJ * 512 * 4;
    void*  pwf    = (void*)extra2;                              // 34816 B pou frags
    float* pprm   = (float*)(extra2 + 2176 * 16);               // 2 KB pou params

    const size_t need = (size_t)2 * NJ * NP * 4 + (size_t)NJ * 1024 * 16
                      + (size_t)NJ * 512 * 4 + 2176 * 16 + 512 * 4;
    const bool use_prep = (ws_size >= need);

    if (use_prep) {
        prep_all_kernel<<<73, 256, 0, stream>>>(sub_W0, sub_b0, sub_Wh, sub_bh, sub_Wl, sub_bl,
                                                pou_W0, pou_b0, pou_Wh, pou_bh, pou_Wl, pou_bl,
                                                (int4v*)swf, sprm, (int4v*)pwf, pprm);
        pou16_kernel<<<NP / 64, 256, 0, stream>>>(x, (const short8*)pwf, pprm, w_all);
        dim3 g2(NP / 256, NJ);
        subnet_nolds_kernel<<<g2, 256, 0, stream>>>(x, (const short8*)swf, sprm, w_all, upart);
    } else {
        pou_mfma_kernel<<<NP / 256, 256, 0, stream>>>(x, pou_W0, pou_b0, pou_Wh, pou_bh,
                                                      pou_Wl, pou_bl, w_all);
        dim3 g2(NP / 256, NJ);
        subnet_mfma_fallback<<<g2, 256, 0, stream>>>(x, sub_W0, sub_b0, sub_Wh, sub_bh,
                                                     sub_Wl, sub_bl, w_all, upart);
    }

    reduce_kernel<<<NP / 256, 256, 0, stream>>>(x, upart, (float*)d_out);
}

// Round 11
// 70.130 us; speedup vs baseline: 1.0108x; 1.0108x over previous
//
#include <hip/hip_runtime.h>
#include <math.h>

#define NP 65536
#define NJ 16
#define WID 64
#define HH 64
#define NPOU 4
#define NSUB 2
#define L2E2 2.8853900817779268f   // 2*log2(e)

typedef __attribute__((ext_vector_type(8))) short short8;
typedef __attribute__((ext_vector_type(4))) float f32x4;
typedef __attribute__((ext_vector_type(4))) int int4v;

// swizzled LDS layout (fallback kernels only)
#define CHUNK_US(row, chunk) ((((row) << 6)) + ((((chunk) ^ ((row) & 7))) << 3))
__device__ __forceinline__ int usIdx(int row, int col) {
    return ((row) << 6) + ((((col >> 3) ^ (row & 7))) << 3) + (col & 7);
}

__device__ __forceinline__ unsigned short f2bf(float f) {   // RNE
    unsigned u = __float_as_uint(f);
    u += 0x7FFFu + ((u >> 16) & 1u);
    return (unsigned short)(u >> 16);
}
__device__ __forceinline__ unsigned short rhu(float f) {
    return (unsigned short)((__float_as_uint(f) + 0x8000u) >> 16);
}
__device__ __forceinline__ unsigned pk2(float a, float b) {
    unsigned ua = __float_as_uint(a) + 0x8000u;
    unsigned ub = __float_as_uint(b) + 0x8000u;
    return __builtin_amdgcn_perm(ub, ua, 0x07060302u);
}
__device__ __forceinline__ unsigned cvtpk(float a, float b) { // HW pack, RNE
    unsigned r;
    asm("v_cvt_pk_bf16_f32 %0, %1, %2" : "=v"(r) : "v"(a), "v"(b));
    return r;
}
__device__ __forceinline__ float bf2f(unsigned short s) {
    return __uint_as_float(((unsigned)s) << 16);
}
// tanh with argument pre-scaled by 2*log2e: tanh(z) = 1 - 2/(2^y+1)
__device__ __forceinline__ float tanh2(float y) {
    float e = __builtin_amdgcn_exp2f(y);
    return fmaf(-2.0f, __builtin_amdgcn_rcpf(e + 1.0f), 1.0f);
}
__device__ __forceinline__ short8 mk8(unsigned a, unsigned b, unsigned c, unsigned d) {
    int4v t; t.x = (int)a; t.y = (int)b; t.z = (int)c; t.w = (int)d;
    return __builtin_bit_cast(short8, t);
}
// C-layout (16 rows {..+4g+q} x col) -> B-frag (k=kn*32+8g+e) pair transform
#define CB_TRANSFORM(hsrc, bfdst)                                              \
    {                                                                          \
        _Pragma("unroll")                                                      \
        for (int kn = 0; kn < 2; ++kn) {                                       \
            unsigned A0 = cvtpk(hsrc[2 * kn][0],     hsrc[2 * kn][1]);         \
            unsigned A1 = cvtpk(hsrc[2 * kn][2],     hsrc[2 * kn][3]);         \
            unsigned B0 = cvtpk(hsrc[2 * kn + 1][0], hsrc[2 * kn + 1][1]);     \
            unsigned B1 = cvtpk(hsrc[2 * kn + 1][2], hsrc[2 * kn + 1][3]);     \
            asm("v_permlane32_swap_b32 %0, %1" : "+v"(A0), "+v"(B0));          \
            asm("v_permlane16_swap_b32 %0, %1" : "+v"(A0), "+v"(B0));          \
            asm("v_permlane32_swap_b32 %0, %1" : "+v"(A1), "+v"(B1));          \
            asm("v_permlane16_swap_b32 %0, %1" : "+v"(A1), "+v"(B1));          \
            bfdst[kn] = mk8(A0, A1, B0, B1);                                   \
        }                                                                      \
    }

// ============== Merged prep: blocks [0,64) = subnet frags/params, [64,73) = pou ==============
__global__ __launch_bounds__(256) void prep_all_kernel(
    const float* __restrict__ sW0, const float* __restrict__ sb0,
    const float* __restrict__ sWh, const float* __restrict__ sbh_,
    const float* __restrict__ sWl, const float* __restrict__ sbl,
    const float* __restrict__ pW0, const float* __restrict__ pb0,
    const float* __restrict__ pWh, const float* __restrict__ pbh,
    const float* __restrict__ pWl, const float* __restrict__ pbl,
    int4v* __restrict__ wfrag, float* __restrict__ prm,
    int4v* __restrict__ pwf,   float* __restrict__ pp)
{
    const int blk = blockIdx.x;
    const int tid = threadIdx.x;

    if (blk < 64) {
        // ---------------- subnet prep ----------------
        const int j  = blk >> 2;
        const int bx = blk & 3;
        const int f  = bx * 256 + tid;
        const int lane = f & 63, kc = (f >> 6) & 1, mt = (f >> 7) & 3, L = f >> 9;
        const int c = lane & 15, g = lane >> 4;
        const int n = mt * 16 + c;

        const float* src = sWh + j * (NSUB * WID * WID) + L * 4096;
        unsigned w[4];
#pragma unroll
        for (int e2 = 0; e2 < 4; ++e2) {
            int k = kc * 32 + 8 * g + 2 * e2;
            float v0 = L2E2 * src[k * 64 + n];
            float v1 = L2E2 * src[(k + 1) * 64 + n];
            w[e2] = (unsigned)f2bf(v0) | ((unsigned)f2bf(v1) << 16);
        }
        int4v r; r.x = (int)w[0]; r.y = (int)w[1]; r.z = (int)w[2]; r.w = (int)w[3];
        wfrag[j * 1024 + f] = r;

        if (bx == 0) {
            float* pj = prm + j * 512;
            if (tid < WID) {
                float w0 = sW0[j * 2 * WID + tid], w1 = sW0[j * 2 * WID + WID + tid];
                pj[tid]       = 2.0f * L2E2 * w0;
                pj[64 + tid]  = 2.0f * L2E2 * w1;
                pj[128 + tid] = L2E2 * (sb0[j * WID + tid] - w0 - w1);
            }
            if (tid < NSUB * WID) pj[192 + tid] = L2E2 * sbh_[j * NSUB * WID + tid];
            if (tid < WID) pj[320 + tid] = sWl[j * WID + tid];
            if (tid == 0) pj[384] = sbl[j];
        }
    } else {
        // ---------------- pou prep ----------------
        const int pb = blk - 64;
        const int idx = pb * 256 + tid;

        if (idx < 2048) {
            const int r = idx >> 9, mt = (idx >> 7) & 3, kc = (idx >> 6) & 1, lane = idx & 63;
            const int c = lane & 15, g = lane >> 4;
            const int n = mt * 16 + c;
            const float* src = pWh + r * 4096;
            unsigned w[4];
#pragma unroll
            for (int e2 = 0; e2 < 4; ++e2) {
                int k = kc * 32 + 8 * g + 2 * e2;
                w[e2] = (unsigned)f2bf(src[k * 64 + n]) | ((unsigned)f2bf(src[(k + 1) * 64 + n]) << 16);
            }
            int4v rr; rr.x = (int)w[0]; rr.y = (int)w[1]; rr.z = (int)w[2]; rr.w = (int)w[3];
            pwf[idx] = rr;
        } else if (idx < 2176) {
            const int t = idx - 2048;
            const int kc = t >> 6, lane = t & 63;
            const int jj = lane & 15, g = lane >> 4;
            unsigned w[4];
#pragma unroll
            for (int e2 = 0; e2 < 4; ++e2) {
                int k = kc * 32 + 8 * g + 2 * e2;
                w[e2] = (unsigned)f2bf(pWl[k * 16 + jj]) | ((unsigned)f2bf(pWl[(k + 1) * 16 + jj]) << 16);
            }
            int4v rr; rr.x = (int)w[0]; rr.y = (int)w[1]; rr.z = (int)w[2]; rr.w = (int)w[3];
            pwf[idx] = rr;
        }
        if (pb == 8) {   // pou param block
            if (tid < HH) {
                pp[tid]       = pW0[tid];
                pp[64 + tid]  = pW0[HH + tid];
                pp[128 + tid] = pb0[tid];
            }
            pp[192 + tid] = pbh[tid];          // 256 entries
            if (tid < NJ) pp[448 + tid] = pbl[tid];
        }
    }
}

// ==== POU, 16 pts/wave, no LDS; writes w_all = softmax * sin(pi x0) sin(pi x1) ====
__global__ __launch_bounds__(256) void pou16_kernel(
    const float* __restrict__ x,
    const short8* __restrict__ pwf, const float* __restrict__ pp,
    float* __restrict__ w_all)
{
    const int tid = threadIdx.x, wave = tid >> 6, lane = tid & 63;
    const int c = lane & 15, g = lane >> 4;
    const int pb = blockIdx.x * 64 + wave * 16;

    float2 xv = ((const float2*)x)[pb + c];

    float trunk[4][4];
#pragma unroll
    for (int mt = 0; mt < 4; ++mt) {
        f32x4 a  = *(const f32x4*)&pp[      mt * 16 + 4 * g];
        f32x4 b  = *(const f32x4*)&pp[ 64 + mt * 16 + 4 * g];
        f32x4 bb = *(const f32x4*)&pp[128 + mt * 16 + 4 * g];
#pragma unroll
        for (int q = 0; q < 4; ++q)
            trunk[mt][q] = fmaxf(fmaf(xv.x, a[q], fmaf(xv.y, b[q], bb[q])), 0.0f);
    }

#pragma unroll
    for (int r = 0; r < NPOU; ++r) {
        short8 bf[2];
        CB_TRANSFORM(trunk, bf);
        f32x4 acc[4];
#pragma unroll
        for (int mt = 0; mt < 4; ++mt)
            acc[mt] = *(const f32x4*)&pp[192 + r * 64 + mt * 16 + 4 * g];
#pragma unroll
        for (int mt = 0; mt < 4; ++mt) {
            short8 a0 = pwf[((r * 4 + mt) * 2 + 0) * 64 + lane];
            short8 a1 = pwf[((r * 4 + mt) * 2 + 1) * 64 + lane];
            acc[mt] = __builtin_amdgcn_mfma_f32_16x16x32_bf16(a0, bf[0], acc[mt], 0, 0, 0);
            acc[mt] = __builtin_amdgcn_mfma_f32_16x16x32_bf16(a1, bf[1], acc[mt], 0, 0, 0);
        }
#pragma unroll
        for (int mt = 0; mt < 4; ++mt)
#pragma unroll
            for (int q = 0; q < 4; ++q)
                trunk[mt][q] += fmaxf(acc[mt][q], 0.0f);
    }

    short8 bfl[2];
    CB_TRANSFORM(trunk, bfl);
    f32x4 lac = *(const f32x4*)&pp[448 + 4 * g];
    lac = __builtin_amdgcn_mfma_f32_16x16x32_bf16(pwf[2048 + lane],      bfl[0], lac, 0, 0, 0);
    lac = __builtin_amdgcn_mfma_f32_16x16x32_bf16(pwf[2048 + 64 + lane], bfl[1], lac, 0, 0, 0);

    float m = fmaxf(fmaxf(lac[0], lac[1]), fmaxf(lac[2], lac[3]));
    m = fmaxf(m, __shfl_xor(m, 16));
    m = fmaxf(m, __shfl_xor(m, 32));
    float ev[4]; float s = 0.0f;
#pragma unroll
    for (int q = 0; q < 4; ++q) { ev[q] = __expf(lac[q] - m); s += ev[q]; }
    s += __shfl_xor(s, 16);
    s += __shfl_xor(s, 32);
    // fold Dirichlet ansatz: sin(pi*x) = v_sin(x/2), x in [0,1]
    const float ss = __builtin_amdgcn_sinf(xv.x * 0.5f) * __builtin_amdgcn_sinf(xv.y * 0.5f);
    const float f = __builtin_amdgcn_rcpf(s) * ss;
#pragma unroll
    for (int q = 0; q < 4; ++q)
        w_all[(4 * g + q) * NP + pb + c] = ev[q] * f;
}

// ======== Subnet, 64 pts/wave, no LDS (R9-proven form); atomic-accumulates into out ========
__global__ __launch_bounds__(256, 4) void subnet_nolds_kernel(
    const float* __restrict__ x,
    const short8* __restrict__ wfrag,
    const float* __restrict__ prm,
    const float* __restrict__ w_all,
    float* __restrict__ out)
{
    const int tid  = threadIdx.x;
    const int j    = blockIdx.y;
    const int wave = tid >> 6;
    const int lane = tid & 63;
    const int c    = lane & 15;
    const int g    = lane >> 4;

    const float*  pj = prm + j * 512;
    const short8* wf = wfrag + j * 1024;
    const int pb = blockIdx.x * 256 + wave * 64;

    // ---- L0 directly in B-frag layout ----
    short8 bf[2][4];
    {
        float xs0[4], xs1[4];
#pragma unroll
        for (int nt = 0; nt < 4; ++nt) {
            float2 xv = ((const float2*)x)[pb + nt * 16 + c];
            xs0[nt] = xv.x; xs1[nt] = xv.y;
        }
        f32x4 wa[2][2], wb[2][2], bb[2][2];
#pragma unroll
        for (int kc = 0; kc < 2; ++kc)
#pragma unroll
            for (int hf = 0; hf < 2; ++hf) {
                wa[kc][hf] = *(const f32x4*)&pj[      kc * 32 + 8 * g + 4 * hf];
                wb[kc][hf] = *(const f32x4*)&pj[ 64 + kc * 32 + 8 * g + 4 * hf];
                bb[kc][hf] = *(const f32x4*)&pj[128 + kc * 32 + 8 * g + 4 * hf];
            }
        unsigned t[2][4][4];
#pragma unroll
        for (int kc = 0; kc < 2; ++kc)
#pragma unroll
            for (int pr = 0; pr < 4; ++pr) {
                const int h0 = pr >> 1, e0 = (2 * pr) & 3, e1 = e0 + 1;
#pragma unroll
                for (int nt = 0; nt < 4; ++nt) {
                    float v0 = tanh2(fmaf(xs0[nt], wa[kc][h0][e0], fmaf(xs1[nt], wb[kc][h0][e0], bb[kc][h0][e0])));
                    float v1 = tanh2(fmaf(xs0[nt], wa[kc][h0][e1], fmaf(xs1[nt], wb[kc][h0][e1], bb[kc][h0][e1])));
                    t[kc][nt][pr] = cvtpk(v0, v1);
                }
            }
#pragma unroll
        for (int kc = 0; kc < 2; ++kc)
#pragma unroll
            for (int nt = 0; nt < 4; ++nt)
                bf[kc][nt] = mk8(t[kc][nt][0], t[kc][nt][1], t[kc][nt][2], t[kc][nt][3]);
    }

    float red[4];
#pragma unroll
    for (int nt = 0; nt < 4; ++nt) red[nt] = 0.0f;

    // ---- hidden layers: A-frags straight from global (L2-resident) ----
#pragma unroll
    for (int L = 0; L < NSUB; ++L) {
        short8 aw[4][2];
#pragma unroll
        for (int mt = 0; mt < 4; ++mt)
#pragma unroll
            for (int kc = 0; kc < 2; ++kc)
                aw[mt][kc] = wf[((L * 4 + mt) * 2 + kc) * 64 + lane];
        f32x4 bias[4];
#pragma unroll
        for (int mt = 0; mt < 4; ++mt)
            bias[mt] = *(const f32x4*)&pj[192 + L * 64 + mt * 16 + 4 * g];

#pragma unroll
        for (int nt = 0; nt < 4; ++nt) {
            f32x4 acc[4];
#pragma unroll
            for (int mt = 0; mt < 4; ++mt) acc[mt] = bias[mt];
#pragma unroll
            for (int mt = 0; mt < 4; ++mt) {
                acc[mt] = __builtin_amdgcn_mfma_f32_16x16x32_bf16(aw[mt][0], bf[0][nt], acc[mt], 0, 0, 0);
                acc[mt] = __builtin_amdgcn_mfma_f32_16x16x32_bf16(aw[mt][1], bf[1][nt], acc[mt], 0, 0, 0);
            }

            if (L < NSUB - 1) {
                float h[4][4];
#pragma unroll
                for (int mt = 0; mt < 4; ++mt)
#pragma unroll
                    for (int q = 0; q < 4; ++q) h[mt][q] = tanh2(acc[mt][q]);
                short8 btmp[2];
                CB_TRANSFORM(h, btmp);
                bf[0][nt] = btmp[0];
                bf[1][nt] = btmp[1];
            } else {
#pragma unroll
                for (int mt = 0; mt < 4; ++mt) {
                    f32x4 wlv = *(const f32x4*)&pj[320 + mt * 16 + 4 * g];
#pragma unroll
                    for (int q = 0; q < 4; ++q)
                        red[nt] = fmaf(tanh2(acc[mt][q]), wlv[q], red[nt]);
                }
            }
        }
    }

#pragma unroll
    for (int nt = 0; nt < 4; ++nt) {
        red[nt] += __shfl_xor(red[nt], 16);
        red[nt] += __shfl_xor(red[nt], 32);
    }
    float u = (g & 1) ? ((g & 2) ? red[3] : red[1]) : ((g & 2) ? red[2] : red[0]);
    u += pj[384];

    const int p = pb + lane;
    atomicAdd(&out[p], u * w_all[j * NP + p]);
}

// ================= Fallback kernels (ws-guard path; proven structure) =========
__global__ __launch_bounds__(256) void pou_mfma_kernel(
    const float* __restrict__ x,
    const float* __restrict__ W0, const float* __restrict__ b0,
    const float* __restrict__ Wh, const float* __restrict__ bh,
    const float* __restrict__ Wl, const float* __restrict__ bl,
    float* __restrict__ w_all)
{
    __shared__ unsigned short sA[4 * 64 * 64];
    __shared__ unsigned short sWhT[NPOU * 64 * 64];
    __shared__ unsigned short sWlT[16 * 64];
    __shared__ float sW0a[HH], sW0b[HH], sB0[HH];
    __shared__ float sbh[NPOU * HH];
    __shared__ float sbl[NJ];

    const int tid  = threadIdx.x;
    const int wave = tid >> 6;
    const int lane = tid & 63;
    const int r15  = lane & 15;
    const int g    = lane >> 4;

    for (int idx = tid; idx < NPOU * HH * HH; idx += 256) {
        int r = idx >> 12, k = (idx >> 6) & 63, n = idx & 63;
        sWhT[r * 4096 + usIdx(n, k)] = f2bf(Wh[idx]);
    }
    for (int idx = tid; idx < HH * NJ; idx += 256) {
        int k = idx >> 4, j = idx & 15;
        sWlT[usIdx(j, k)] = f2bf(Wl[idx]);
    }
    if (tid < HH) { sW0a[tid] = W0[tid]; sW0b[tid] = W0[HH + tid]; sB0[tid] = b0[tid]; }
    for (int i = tid; i < NPOU * HH; i += 256) sbh[i] = bh[i];
    if (tid < NJ) sbl[tid] = bl[tid];
    __syncthreads();

    unsigned short* myA = &sA[wave * 4096];
    const int pbase = blockIdx.x * 256;

    {
        const int p = pbase + tid;
        float2 xv = ((const float2*)x)[p];
        float v[HH];
#pragma unroll
        for (int c = 0; c < HH; ++c)
            v[c] = fmaxf(fmaf(xv.x, sW0a[c], fmaf(xv.y, sW0b[c], sB0[c])), 0.0f);
#pragma unroll
        for (int c = 0; c < 8; ++c) {
            int4v r;
            r.x = (int)pk2(v[8 * c + 0], v[8 * c + 1]);
            r.y = (int)pk2(v[8 * c + 2], v[8 * c + 3]);
            r.z = (int)pk2(v[8 * c + 4], v[8 * c + 5]);
            r.w = (int)pk2(v[8 * c + 6], v[8 * c + 7]);
            *(int4v*)&myA[CHUNK_US(lane, c)] = r;
        }
    }

    float trunk[4][4][4];
#pragma unroll
    for (int mt = 0; mt < 4; ++mt)
#pragma unroll
        for (int nt = 0; nt < 4; ++nt)
#pragma unroll
            for (int q = 0; q < 4; ++q)
                trunk[mt][nt][q] = bf2f(myA[usIdx(mt * 16 + g * 4 + q, nt * 16 + r15)]);

#pragma unroll 1
    for (int r = 0; r < NPOU; ++r) {
        const unsigned short* wt = &sWhT[r * 4096];
        short8 bfr[2][4];
#pragma unroll
        for (int kc = 0; kc < 2; ++kc)
#pragma unroll
            for (int nt = 0; nt < 4; ++nt)
                bfr[kc][nt] = *(const short8*)&wt[CHUNK_US(nt * 16 + r15, kc * 4 + g)];
        float bias[4];
#pragma unroll
        for (int nt = 0; nt < 4; ++nt) bias[nt] = sbh[r * HH + nt * 16 + r15];

#pragma unroll
        for (int mt = 0; mt < 4; ++mt) {
            short8 a0 = *(const short8*)&myA[CHUNK_US(mt * 16 + r15, g)];
            short8 a1 = *(const short8*)&myA[CHUNK_US(mt * 16 + r15, 4 + g)];
            f32x4 acc[4];
#pragma unroll
            for (int nt = 0; nt < 4; ++nt) {
                acc[nt] = (f32x4)(0.0f);
                acc[nt] = __builtin_amdgcn_mfma_f32_16x16x32_bf16(a0, bfr[0][nt], acc[nt], 0, 0, 0);
                acc[nt] = __builtin_amdgcn_mfma_f32_16x16x32_bf16(a1, bfr[1][nt], acc[nt], 0, 0, 0);
            }
#pragma unroll
            for (int nt = 0; nt < 4; ++nt)
#pragma unroll
                for (int q = 0; q < 4; ++q) {
                    float t = trunk[mt][nt][q] + fmaxf(acc[nt][q] + bias[nt], 0.0f);
                    trunk[mt][nt][q] = t;
                    myA[usIdx(mt * 16 + g * 4 + q, nt * 16 + r15)] = rhu(t);
                }
        }
    }

    short8 bw0 = *(const short8*)&sWlT[CHUNK_US(r15, g)];
    short8 bw1 = *(const short8*)&sWlT[CHUNK_US(r15, 4 + g)];
    float lg[4][4], mx[4][4];
#pragma unroll
    for (int mt = 0; mt < 4; ++mt) {
        short8 a0 = *(const short8*)&myA[CHUNK_US(mt * 16 + r15, g)];
        short8 a1 = *(const short8*)&myA[CHUNK_US(mt * 16 + r15, 4 + g)];
        f32x4 acc = (f32x4)(0.0f);
        acc = __builtin_amdgcn_mfma_f32_16x16x32_bf16(a0, bw0, acc, 0, 0, 0);
        acc = __builtin_amdgcn_mfma_f32_16x16x32_bf16(a1, bw1, acc, 0, 0, 0);
#pragma unroll
        for (int q = 0; q < 4; ++q) { lg[mt][q] = acc[q] + sbl[r15]; mx[mt][q] = lg[mt][q]; }
    }
#pragma unroll
    for (int mask = 1; mask < 16; mask <<= 1)
#pragma unroll
        for (int mt = 0; mt < 4; ++mt)
#pragma unroll
            for (int q = 0; q < 4; ++q) mx[mt][q] = fmaxf(mx[mt][q], __shfl_xor(mx[mt][q], mask));
    float ev[4][4], sm[4][4];
#pragma unroll
    for (int mt = 0; mt < 4; ++mt)
#pragma unroll
        for (int q = 0; q < 4; ++q) { ev[mt][q] = __expf(lg[mt][q] - mx[mt][q]); sm[mt][q] = ev[mt][q]; }
#pragma unroll
    for (int mask = 1; mask < 16; mask <<= 1)
#pragma unroll
        for (int mt = 0; mt < 4; ++mt)
#pragma unroll
            for (int q = 0; q < 4; ++q) sm[mt][q] += __shfl_xor(sm[mt][q], mask);
#pragma unroll
    for (int mt = 0; mt < 4; ++mt)
#pragma unroll
        for (int q = 0; q < 4; ++q) {
            const int p = pbase + wave * 64 + mt * 16 + g * 4 + q;
            w_all[r15 * NP + p] = ev[mt][q] * __builtin_amdgcn_rcpf(sm[mt][q]);
        }
}

__global__ __launch_bounds__(256) void subnet_mfma_fallback(
    const float* __restrict__ x,
    const float* __restrict__ gW0, const float* __restrict__ gb0,
    const float* __restrict__ gWh, const float* __restrict__ gbh,
    const float* __restrict__ gWl, const float* __restrict__ gbl,
    const float* __restrict__ w_all,
    float* __restrict__ upart)
{
    __shared__ __align__(16) unsigned short sWt[NSUB * 64 * 64];
    __shared__ __align__(16) float sW0a[WID], sW0b[WID], sB0[WID];
    __shared__ __align__(16) float sbh[NSUB * WID];
    __shared__ __align__(16) float sWl[WID];
    __shared__ float sbl1v;

    const int tid  = threadIdx.x;
    const int j    = blockIdx.y;
    const int wave = tid >> 6;
    const int lane = tid & 63;
    const int c    = lane & 15;
    const int g    = lane >> 4;

    {
        const float* src = gWh + j * (NSUB * WID * WID);
        for (int idx = tid; idx < NSUB * WID * WID; idx += 256) {
            int L = idx >> 12, rem = idx & 4095;
            int k = rem >> 6, n = rem & 63;
            sWt[L * 4096 + usIdx(n, k)] = f2bf(L2E2 * src[idx]);
        }
        if (tid < WID) {
            float w0 = gW0[j * 2 * WID + tid], w1 = gW0[j * 2 * WID + WID + tid];
            sW0a[tid] = 2.0f * L2E2 * w0;
            sW0b[tid] = 2.0f * L2E2 * w1;
            sB0[tid]  = L2E2 * (gb0[j * WID + tid] - w0 - w1);
        }
        if (tid < NSUB * WID) sbh[tid] = L2E2 * gbh[j * NSUB * WID + tid];
        if (tid < WID) sWl[tid] = gWl[j * WID + tid];
        if (tid == 0) sbl1v = gbl[j];
    }
    __syncthreads();

    const int pb = blockIdx.x * 256 + wave * 64;

    short8 bf[2][4];
    {
        float xs0[4], xs1[4];
#pragma unroll
        for (int nt = 0; nt < 4; ++nt) {
            float2 xv = ((const float2*)x)[pb + nt * 16 + c];
            xs0[nt] = xv.x; xs1[nt] = xv.y;
        }
        f32x4 wa[2][2], wb[2][2], bb[2][2];
#pragma unroll
        for (int kc = 0; kc < 2; ++kc)
#pragma unroll
            for (int hf = 0; hf < 2; ++hf) {
                wa[kc][hf] = *(const f32x4*)&sW0a[kc * 32 + 8 * g + 4 * hf];
                wb[kc][hf] = *(const f32x4*)&sW0b[kc * 32 + 8 * g + 4 * hf];
                bb[kc][hf] = *(const f32x4*)&sB0 [kc * 32 + 8 * g + 4 * hf];
            }
        unsigned t[2][4][4];
#pragma unroll
        for (int kc = 0; kc < 2; ++kc)
#pragma unroll
            for (int pr = 0; pr < 4; ++pr) {
                const int h0 = pr >> 1, e0 = (2 * pr) & 3, e1 = e0 + 1;
#pragma unroll
                for (int nt = 0; nt < 4; ++nt) {
                    float v0 = tanh2(fmaf(xs0[nt], wa[kc][h0][e0], fmaf(xs1[nt], wb[kc][h0][e0], bb[kc][h0][e0])));
                    float v1 = tanh2(fmaf(xs0[nt], wa[kc][h0][e1], fmaf(xs1[nt], wb[kc][h0][e1], bb[kc][h0][e1])));
                    t[kc][nt][pr] = cvtpk(v0, v1);
                }
            }
#pragma unroll
        for (int kc = 0; kc < 2; ++kc)
#pragma unroll
            for (int nt = 0; nt < 4; ++nt)
                bf[kc][nt] = mk8(t[kc][nt][0], t[kc][nt][1], t[kc][nt][2], t[kc][nt][3]);
    }

    float red[4];
#pragma unroll
    for (int nt = 0; nt < 4; ++nt) red[nt] = 0.0f;

#pragma unroll
    for (int L = 0; L < NSUB; ++L) {
        const unsigned short* wt = &sWt[L * 4096];
        short8 aw[4][2];
#pragma unroll
        for (int mt = 0; mt < 4; ++mt)
#pragma unroll
            for (int kc = 0; kc < 2; ++kc)
                aw[mt][kc] = *(const short8*)&wt[CHUNK_US(mt * 16 + c, kc * 4 + g)];
        f32x4 bias[4];
#pragma unroll
        for (int mt = 0; mt < 4; ++mt)
            bias[mt] = *(const f32x4*)&sbh[L * 64 + mt * 16 + 4 * g];

#pragma unroll
        for (int nt = 0; nt < 4; ++nt) {
            f32x4 acc[4];
#pragma unroll
            for (int mt = 0; mt < 4; ++mt) acc[mt] = bias[mt];
#pragma unroll
            for (int mt = 0; mt < 4; ++mt) {
                acc[mt] = __builtin_amdgcn_mfma_f32_16x16x32_bf16(aw[mt][0], bf[0][nt], acc[mt], 0, 0, 0);
                acc[mt] = __builtin_amdgcn_mfma_f32_16x16x32_bf16(aw[mt][1], bf[1][nt], acc[mt], 0, 0, 0);
            }

            if (L < NSUB - 1) {
                float h[4][4];
#pragma unroll
                for (int mt = 0; mt < 4; ++mt)
#pragma unroll
                    for (int q = 0; q < 4; ++q) h[mt][q] = tanh2(acc[mt][q]);
                short8 btmp[2];
                CB_TRANSFORM(h, btmp);
                bf[0][nt] = btmp[0];
                bf[1][nt] = btmp[1];
            } else {
#pragma unroll
                for (int mt = 0; mt < 4; ++mt) {
                    f32x4 wlv = *(const f32x4*)&sWl[mt * 16 + 4 * g];
#pragma unroll
                    for (int q = 0; q < 4; ++q)
                        red[nt] = fmaf(tanh2(acc[mt][q]), wlv[q], red[nt]);
                }
            }
        }
    }

#pragma unroll
    for (int nt = 0; nt < 4; ++nt) {
        red[nt] += __shfl_xor(red[nt], 16);
        red[nt] += __shfl_xor(red[nt], 32);
    }
    float u = (g & 1) ? ((g & 2) ? red[3] : red[1]) : ((g & 2) ? red[2] : red[0]);
    u += sbl1v;

    const int p = pb + lane;
    upart[j * NP + p] = u * w_all[j * NP + p];
}

// ============ Reduce (fallback path only) ============
__global__ __launch_bounds__(256) void reduce_kernel(
    const float* __restrict__ x,
    const float* __restrict__ upart,
    float* __restrict__ out)
{
    const int p = blockIdx.x * 256 + threadIdx.x;
    float s = 0.0f;
#pragma unroll
    for (int j = 0; j < NJ; ++j) s += upart[j * NP + p];
    float2 xv = ((const float2*)x)[p];
    float s0 = __builtin_amdgcn_sinf(xv.x * 0.5f);
    float s1 = __builtin_amdgcn_sinf(xv.y * 0.5f);
    out[p] = s * s0 * s1;
}

extern "C" void kernel_launch(void* const* d_in, const int* in_sizes, int n_in,
                              void* d_out, int out_size, void* d_ws, size_t ws_size,
                              hipStream_t stream) {
    const float* x      = (const float*)d_in[0];
    const float* sub_W0 = (const float*)d_in[1];
    const float* sub_b0 = (const float*)d_in[2];
    const float* sub_Wh = (const float*)d_in[3];
    const float* sub_bh = (const float*)d_in[4];
    const float* sub_Wl = (const float*)d_in[5];
    const float* sub_bl = (const float*)d_in[6];
    const float* pou_W0 = (const float*)d_in[7];
    const float* pou_b0 = (const float*)d_in[8];
    const float* pou_Wh = (const float*)d_in[9];
    const float* pou_bh = (const float*)d_in[10];
    const float* pou_Wl = (const float*)d_in[11];
    const float* pou_bl = (const float*)d_in[12];

    float* w_all = (float*)d_ws;                   // [J][P] 4 MB
    float* upart = (float*)d_ws + (size_t)NJ * NP; // [J][P] 4 MB (fallback only)
    char*  extra  = (char*)d_ws + (size_t)2 * NJ * NP * 4;
    void*  swf    = (void*)extra;                               // 256 KB subnet frags
    float* sprm   = (float*)(extra + (size_t)NJ * 1024 * 16);   // 32 KB subnet params
    char*  extra2 = extra + (size_t)NJ * 1024 * 16 + (size_t)NJ * 512 * 4;
    void*  pwf    = (void*)extra2;                              // 34816 B pou frags
    float* pprm   = (float*)(extra2 + 2176 * 16);               // 2 KB pou params

    const size_t need = (size_t)2 * NJ * NP * 4 + (size_t)NJ * 1024 * 16
                      + (size_t)NJ * 512 * 4 + 2176 * 16 + 512 * 4;
    const bool use_prep = (ws_size >= need);

    if (use_prep) {
        // out accumulated by atomics -> zero it each call (capture-safe async memset)
        hipMemsetAsync(d_out, 0, (size_t)out_size * sizeof(float), stream);
        prep_all_kernel<<<73, 256, 0, stream>>>(sub_W0, sub_b0, sub_Wh, sub_bh, sub_Wl, sub_bl,
                                                pou_W0, pou_b0, pou_Wh, pou_bh, pou_Wl, pou_bl,
                                                (int4v*)swf, sprm, (int4v*)pwf, pprm);
        pou16_kernel<<<NP / 64, 256, 0, stream>>>(x, (const short8*)pwf, pprm, w_all);
        dim3 g2(NP / 256, NJ);
        subnet_nolds_kernel<<<g2, 256, 0, stream>>>(x, (const short8*)swf, sprm, w_all,
                                                    (float*)d_out);
    } else {
        pou_mfma_kernel<<<NP / 256, 256, 0, stream>>>(x, pou_W0, pou_b0, pou_Wh, pou_bh,
                                                      pou_Wl, pou_bl, w_all);
        dim3 g2(NP / 256, NJ);
        subnet_mfma_fallback<<<g2, 256, 0, stream>>>(x, sub_W0, sub_b0, sub_Wh, sub_bh,
                                                     sub_Wl, sub_bl, w_all, upart);
        reduce_kernel<<<NP / 256, 256, 0, stream>>>(x, upart, (float*)d_out);
    }
}

// Round 12
// 68.054 us; speedup vs baseline: 1.0417x; 1.0305x over previous
//
#include <hip/hip_runtime.h>
#include <math.h>

#define NP 65536
#define NJ 16
#define WID 64
#define HH 64
#define NPOU 4
#define NSUB 2
#define L2E2 2.8853900817779268f   // 2*log2(e)

typedef __attribute__((ext_vector_type(8))) short short8;
typedef __attribute__((ext_vector_type(4))) float f32x4;
typedef __attribute__((ext_vector_type(4))) int int4v;

// swizzled LDS layout (fallback kernels only)
#define CHUNK_US(row, chunk) ((((row) << 6)) + ((((chunk) ^ ((row) & 7))) << 3))
__device__ __forceinline__ int usIdx(int row, int col) {
    return ((row) << 6) + ((((col >> 3) ^ (row & 7))) << 3) + (col & 7);
}

__device__ __forceinline__ unsigned short f2bf(float f) {   // RNE
    unsigned u = __float_as_uint(f);
    u += 0x7FFFu + ((u >> 16) & 1u);
    return (unsigned short)(u >> 16);
}
__device__ __forceinline__ unsigned short rhu(float f) {
    return (unsigned short)((__float_as_uint(f) + 0x8000u) >> 16);
}
__device__ __forceinline__ unsigned pk2(float a, float b) {
    unsigned ua = __float_as_uint(a) + 0x8000u;
    unsigned ub = __float_as_uint(b) + 0x8000u;
    return __builtin_amdgcn_perm(ub, ua, 0x07060302u);
}
__device__ __forceinline__ unsigned cvtpk(float a, float b) { // HW pack, RNE
    unsigned r;
    asm("v_cvt_pk_bf16_f32 %0, %1, %2" : "=v"(r) : "v"(a), "v"(b));
    return r;
}
__device__ __forceinline__ float bf2f(unsigned short s) {
    return __uint_as_float(((unsigned)s) << 16);
}
// tanh with argument pre-scaled by 2*log2e: tanh(z) = 1 - 2/(2^y+1)
__device__ __forceinline__ float tanh2(float y) {
    float e = __builtin_amdgcn_exp2f(y);
    return fmaf(-2.0f, __builtin_amdgcn_rcpf(e + 1.0f), 1.0f);
}
__device__ __forceinline__ short8 mk8(unsigned a, unsigned b, unsigned c, unsigned d) {
    int4v t; t.x = (int)a; t.y = (int)b; t.z = (int)c; t.w = (int)d;
    return __builtin_bit_cast(short8, t);
}
// C-layout (16 rows {..+4g+q} x col) -> B-frag (k=kn*32+8g+e) pair transform
#define CB_TRANSFORM(hsrc, bfdst)                                              \
    {                                                                          \
        _Pragma("unroll")                                                      \
        for (int kn = 0; kn < 2; ++kn) {                                       \
            unsigned A0 = cvtpk(hsrc[2 * kn][0],     hsrc[2 * kn][1]);         \
            unsigned A1 = cvtpk(hsrc[2 * kn][2],     hsrc[2 * kn][3]);         \
            unsigned B0 = cvtpk(hsrc[2 * kn + 1][0], hsrc[2 * kn + 1][1]);     \
            unsigned B1 = cvtpk(hsrc[2 * kn + 1][2], hsrc[2 * kn + 1][3]);     \
            asm("v_permlane32_swap_b32 %0, %1" : "+v"(A0), "+v"(B0));          \
            asm("v_permlane16_swap_b32 %0, %1" : "+v"(A0), "+v"(B0));          \
            asm("v_permlane32_swap_b32 %0, %1" : "+v"(A1), "+v"(B1));          \
            asm("v_permlane16_swap_b32 %0, %1" : "+v"(A1), "+v"(B1));          \
            bfdst[kn] = mk8(A0, A1, B0, B1);                                   \
        }                                                                      \
    }

// == Merged prep: [0,64)=subnet Wh frags/params, [64,73)=pou, [73,89)=subnet L0 A-frags ==
__global__ __launch_bounds__(256) void prep_all_kernel(
    const float* __restrict__ sW0, const float* __restrict__ sb0,
    const float* __restrict__ sWh, const float* __restrict__ sbh_,
    const float* __restrict__ sWl, const float* __restrict__ sbl,
    const float* __restrict__ pW0, const float* __restrict__ pb0,
    const float* __restrict__ pWh, const float* __restrict__ pbh,
    const float* __restrict__ pWl, const float* __restrict__ pbl,
    int4v* __restrict__ wfrag, float* __restrict__ prm,
    int4v* __restrict__ pwf,   float* __restrict__ pp,
    int4v* __restrict__ wfrag0)
{
    const int blk = blockIdx.x;
    const int tid = threadIdx.x;

    if (blk < 64) {
        // ---------------- subnet Wh frags + params ----------------
        const int j  = blk >> 2;
        const int bx = blk & 3;
        const int f  = bx * 256 + tid;
        const int lane = f & 63, kc = (f >> 6) & 1, mt = (f >> 7) & 3, L = f >> 9;
        const int c = lane & 15, g = lane >> 4;
        const int n = mt * 16 + c;

        const float* src = sWh + j * (NSUB * WID * WID) + L * 4096;
        unsigned w[4];
#pragma unroll
        for (int e2 = 0; e2 < 4; ++e2) {
            int k = kc * 32 + 8 * g + 2 * e2;
            float v0 = L2E2 * src[k * 64 + n];
            float v1 = L2E2 * src[(k + 1) * 64 + n];
            w[e2] = (unsigned)f2bf(v0) | ((unsigned)f2bf(v1) << 16);
        }
        int4v r; r.x = (int)w[0]; r.y = (int)w[1]; r.z = (int)w[2]; r.w = (int)w[3];
        wfrag[j * 1024 + f] = r;

        if (bx == 0) {
            float* pj = prm + j * 512;
            if (tid < WID) {
                float w0 = sW0[j * 2 * WID + tid], w1 = sW0[j * 2 * WID + WID + tid];
                pj[tid]       = 2.0f * L2E2 * w0;
                pj[64 + tid]  = 2.0f * L2E2 * w1;
                pj[128 + tid] = L2E2 * (sb0[j * WID + tid] - w0 - w1);   // L0 bias (C-init)
            }
            if (tid < NSUB * WID) pj[192 + tid] = L2E2 * sbh_[j * NSUB * WID + tid];
            if (tid < WID) pj[320 + tid] = sWl[j * WID + tid];
            if (tid == 0) pj[384] = sbl[j];
        }
    } else if (blk < 73) {
        // ---------------- pou prep ----------------
        const int pb = blk - 64;
        const int idx = pb * 256 + tid;

        if (idx < 2048) {
            const int r = idx >> 9, mt = (idx >> 7) & 3, kc = (idx >> 6) & 1, lane = idx & 63;
            const int c = lane & 15, g = lane >> 4;
            const int n = mt * 16 + c;
            const float* src = pWh + r * 4096;
            unsigned w[4];
#pragma unroll
            for (int e2 = 0; e2 < 4; ++e2) {
                int k = kc * 32 + 8 * g + 2 * e2;
                w[e2] = (unsigned)f2bf(src[k * 64 + n]) | ((unsigned)f2bf(src[(k + 1) * 64 + n]) << 16);
            }
            int4v rr; rr.x = (int)w[0]; rr.y = (int)w[1]; rr.z = (int)w[2]; rr.w = (int)w[3];
            pwf[idx] = rr;
        } else if (idx < 2176) {
            const int t = idx - 2048;
            const int kc = t >> 6, lane = t & 63;
            const int jj = lane & 15, g = lane >> 4;
            unsigned w[4];
#pragma unroll
            for (int e2 = 0; e2 < 4; ++e2) {
                int k = kc * 32 + 8 * g + 2 * e2;
                w[e2] = (unsigned)f2bf(pWl[k * 16 + jj]) | ((unsigned)f2bf(pWl[(k + 1) * 16 + jj]) << 16);
            }
            int4v rr; rr.x = (int)w[0]; rr.y = (int)w[1]; rr.z = (int)w[2]; rr.w = (int)w[3];
            pwf[idx] = rr;
        }
        if (pb == 8) {   // pou param block
            if (tid < HH) {
                pp[tid]       = pW0[tid];
                pp[64 + tid]  = pW0[HH + tid];
                pp[128 + tid] = pb0[tid];
            }
            pp[192 + tid] = pbh[tid];          // 256 entries
            if (tid < NJ) pp[448 + tid] = pbl[tid];
        }
    } else {
        // ---- subnet L0 A-frags: k0..k5 = (w0h, w1h, w0h, w1h, w0l, w1l) hi/lo split ----
        const int t = (blk - 73) * 256 + tid;      // [0, 4096)
        const int j = t >> 8, rem = t & 255;
        const int mt = rem >> 6, lane = rem & 63;
        const int c = lane & 15, g = lane >> 4;
        const int n = mt * 16 + c;
        unsigned r0 = 0, r1 = 0, r2 = 0;
        if (g == 0) {
            float w0c = 2.0f * L2E2 * sW0[j * 2 * WID + n];
            float w1c = 2.0f * L2E2 * sW0[j * 2 * WID + WID + n];
            unsigned short h0 = f2bf(w0c), h1 = f2bf(w1c);
            unsigned short l0 = f2bf(w0c - bf2f(h0));
            unsigned short l1 = f2bf(w1c - bf2f(h1));
            r0 = (unsigned)h0 | ((unsigned)h1 << 16);
            r1 = r0;
            r2 = (unsigned)l0 | ((unsigned)l1 << 16);
        }
        int4v rr; rr.x = (int)r0; rr.y = (int)r1; rr.z = (int)r2; rr.w = 0;
        wfrag0[j * 256 + mt * 64 + lane] = rr;
    }
}

// ==== POU, 16 pts/wave, no LDS; w_all = softmax * sin(pi x0) sin(pi x1); zeroes out ====
__global__ __launch_bounds__(256) void pou16_kernel(
    const float* __restrict__ x,
    const short8* __restrict__ pwf, const float* __restrict__ pp,
    float* __restrict__ w_all, float* __restrict__ outz)
{
    const int tid = threadIdx.x, wave = tid >> 6, lane = tid & 63;
    const int c = lane & 15, g = lane >> 4;
    const int pb = blockIdx.x * 64 + wave * 16;

    // zero the atomic accumulation target (runs before subnet in stream order)
    if (tid < 16) ((f32x4*)outz)[blockIdx.x * 16 + tid] = (f32x4)(0.0f);

    float2 xv = ((const float2*)x)[pb + c];

    float trunk[4][4];
#pragma unroll
    for (int mt = 0; mt < 4; ++mt) {
        f32x4 a  = *(const f32x4*)&pp[      mt * 16 + 4 * g];
        f32x4 b  = *(const f32x4*)&pp[ 64 + mt * 16 + 4 * g];
        f32x4 bb = *(const f32x4*)&pp[128 + mt * 16 + 4 * g];
#pragma unroll
        for (int q = 0; q < 4; ++q)
            trunk[mt][q] = fmaxf(fmaf(xv.x, a[q], fmaf(xv.y, b[q], bb[q])), 0.0f);
    }

#pragma unroll
    for (int r = 0; r < NPOU; ++r) {
        short8 bf[2];
        CB_TRANSFORM(trunk, bf);
        f32x4 acc[4];
#pragma unroll
        for (int mt = 0; mt < 4; ++mt)
            acc[mt] = *(const f32x4*)&pp[192 + r * 64 + mt * 16 + 4 * g];
#pragma unroll
        for (int mt = 0; mt < 4; ++mt) {
            short8 a0 = pwf[((r * 4 + mt) * 2 + 0) * 64 + lane];
            short8 a1 = pwf[((r * 4 + mt) * 2 + 1) * 64 + lane];
            acc[mt] = __builtin_amdgcn_mfma_f32_16x16x32_bf16(a0, bf[0], acc[mt], 0, 0, 0);
            acc[mt] = __builtin_amdgcn_mfma_f32_16x16x32_bf16(a1, bf[1], acc[mt], 0, 0, 0);
        }
#pragma unroll
        for (int mt = 0; mt < 4; ++mt)
#pragma unroll
            for (int q = 0; q < 4; ++q)
                trunk[mt][q] += fmaxf(acc[mt][q], 0.0f);
    }

    short8 bfl[2];
    CB_TRANSFORM(trunk, bfl);
    f32x4 lac = *(const f32x4*)&pp[448 + 4 * g];
    lac = __builtin_amdgcn_mfma_f32_16x16x32_bf16(pwf[2048 + lane],      bfl[0], lac, 0, 0, 0);
    lac = __builtin_amdgcn_mfma_f32_16x16x32_bf16(pwf[2048 + 64 + lane], bfl[1], lac, 0, 0, 0);

    float m = fmaxf(fmaxf(lac[0], lac[1]), fmaxf(lac[2], lac[3]));
    m = fmaxf(m, __shfl_xor(m, 16));
    m = fmaxf(m, __shfl_xor(m, 32));
    float ev[4]; float s = 0.0f;
#pragma unroll
    for (int q = 0; q < 4; ++q) { ev[q] = __expf(lac[q] - m); s += ev[q]; }
    s += __shfl_xor(s, 16);
    s += __shfl_xor(s, 32);
    // fold Dirichlet ansatz: sin(pi*x) = v_sin(x/2), x in [0,1]
    const float ss = __builtin_amdgcn_sinf(xv.x * 0.5f) * __builtin_amdgcn_sinf(xv.y * 0.5f);
    const float f = __builtin_amdgcn_rcpf(s) * ss;
#pragma unroll
    for (int q = 0; q < 4; ++q)
        w_all[(4 * g + q) * NP + pb + c] = ev[q] * f;
}

// ======== Subnet, 64 pts/wave, no LDS; L0 via MFMA (hi/lo x,W0); atomic out ========
__global__ __launch_bounds__(256, 4) void subnet_nolds_kernel(
    const float* __restrict__ x,
    const short8* __restrict__ wfrag,
    const short8* __restrict__ wfrag0,
    const float* __restrict__ prm,
    const float* __restrict__ w_all,
    float* __restrict__ out)
{
    const int tid  = threadIdx.x;
    const int j    = blockIdx.y;
    const int wave = tid >> 6;
    const int lane = tid & 63;
    const int c    = lane & 15;
    const int g    = lane >> 4;

    const float*  pj  = prm + j * 512;
    const short8* wf  = wfrag + j * 1024;
    const short8* wf0 = wfrag0 + j * 256;
    const int pb = blockIdx.x * 256 + wave * 64;

    // ---- L0 via MFMA: A = W0 coeff frags (hi/lo), B from x, bias as C-init ----
    short8 aw0[4];
#pragma unroll
    for (int mt = 0; mt < 4; ++mt) aw0[mt] = wf0[mt * 64 + lane];
    f32x4 bias0[4];
#pragma unroll
    for (int mt = 0; mt < 4; ++mt)
        bias0[mt] = *(const f32x4*)&pj[128 + mt * 16 + 4 * g];

    short8 bf[2][4];
#pragma unroll
    for (int nt = 0; nt < 4; ++nt) {
        float2 xv = ((const float2*)x)[pb + nt * 16 + c];
        unsigned r0 = cvtpk(xv.x, xv.y);                      // (x0h, x1h)
        float x0l = xv.x - __uint_as_float(r0 << 16);
        float x1l = xv.y - __uint_as_float(r0 & 0xffff0000u);
        unsigned r1 = cvtpk(x0l, x1l);                        // (x0l, x1l)
        short8 bx = mk8(r0, r1, r0, 0u);                      // k0..5 = x0h,x1h,x0l,x1l,x0h,x1h

        f32x4 acc[4];
#pragma unroll
        for (int mt = 0; mt < 4; ++mt)
            acc[mt] = __builtin_amdgcn_mfma_f32_16x16x32_bf16(aw0[mt], bx, bias0[mt], 0, 0, 0);

        float h[4][4];
#pragma unroll
        for (int mt = 0; mt < 4; ++mt)
#pragma unroll
            for (int q = 0; q < 4; ++q) h[mt][q] = tanh2(acc[mt][q]);
        short8 btmp[2];
        CB_TRANSFORM(h, btmp);
        bf[0][nt] = btmp[0];
        bf[1][nt] = btmp[1];
    }

    float red[4];
#pragma unroll
    for (int nt = 0; nt < 4; ++nt) red[nt] = 0.0f;

    // ---- hidden layers: A-frags straight from global (L2-resident) ----
#pragma unroll
    for (int L = 0; L < NSUB; ++L) {
        short8 aw[4][2];
#pragma unroll
        for (int mt = 0; mt < 4; ++mt)
#pragma unroll
            for (int kc = 0; kc < 2; ++kc)
                aw[mt][kc] = wf[((L * 4 + mt) * 2 + kc) * 64 + lane];
        f32x4 bias[4];
#pragma unroll
        for (int mt = 0; mt < 4; ++mt)
            bias[mt] = *(const f32x4*)&pj[192 + L * 64 + mt * 16 + 4 * g];

#pragma unroll
        for (int nt = 0; nt < 4; ++nt) {
            f32x4 acc[4];
#pragma unroll
            for (int mt = 0; mt < 4; ++mt) acc[mt] = bias[mt];
#pragma unroll
            for (int mt = 0; mt < 4; ++mt) {
                acc[mt] = __builtin_amdgcn_mfma_f32_16x16x32_bf16(aw[mt][0], bf[0][nt], acc[mt], 0, 0, 0);
                acc[mt] = __builtin_amdgcn_mfma_f32_16x16x32_bf16(aw[mt][1], bf[1][nt], acc[mt], 0, 0, 0);
            }

            if (L < NSUB - 1) {
                float h[4][4];
#pragma unroll
                for (int mt = 0; mt < 4; ++mt)
#pragma unroll
                    for (int q = 0; q < 4; ++q) h[mt][q] = tanh2(acc[mt][q]);
                short8 btmp[2];
                CB_TRANSFORM(h, btmp);
                bf[0][nt] = btmp[0];
                bf[1][nt] = btmp[1];
            } else {
#pragma unroll
                for (int mt = 0; mt < 4; ++mt) {
                    f32x4 wlv = *(const f32x4*)&pj[320 + mt * 16 + 4 * g];
#pragma unroll
                    for (int q = 0; q < 4; ++q)
                        red[nt] = fmaf(tanh2(acc[mt][q]), wlv[q], red[nt]);
                }
            }
        }
    }

#pragma unroll
    for (int nt = 0; nt < 4; ++nt) {
        red[nt] += __shfl_xor(red[nt], 16);
        red[nt] += __shfl_xor(red[nt], 32);
    }
    float u = (g & 1) ? ((g & 2) ? red[3] : red[1]) : ((g & 2) ? red[2] : red[0]);
    u += pj[384];

    const int p = pb + lane;
    atomicAdd(&out[p], u * w_all[j * NP + p]);
}

// ================= Fallback kernels (ws-guard path; proven structure) =========
__global__ __launch_bounds__(256) void pou_mfma_kernel(
    const float* __restrict__ x,
    const float* __restrict__ W0, const float* __restrict__ b0,
    const float* __restrict__ Wh, const float* __restrict__ bh,
    const float* __restrict__ Wl, const float* __restrict__ bl,
    float* __restrict__ w_all)
{
    __shared__ unsigned short sA[4 * 64 * 64];
    __shared__ unsigned short sWhT[NPOU * 64 * 64];
    __shared__ unsigned short sWlT[16 * 64];
    __shared__ float sW0a[HH], sW0b[HH], sB0[HH];
    __shared__ float sbh[NPOU * HH];
    __shared__ float sbl[NJ];

    const int tid  = threadIdx.x;
    const int wave = tid >> 6;
    const int lane = tid & 63;
    const int r15  = lane & 15;
    const int g    = lane >> 4;

    for (int idx = tid; idx < NPOU * HH * HH; idx += 256) {
        int r = idx >> 12, k = (idx >> 6) & 63, n = idx & 63;
        sWhT[r * 4096 + usIdx(n, k)] = f2bf(Wh[idx]);
    }
    for (int idx = tid; idx < HH * NJ; idx += 256) {
        int k = idx >> 4, j = idx & 15;
        sWlT[usIdx(j, k)] = f2bf(Wl[idx]);
    }
    if (tid < HH) { sW0a[tid] = W0[tid]; sW0b[tid] = W0[HH + tid]; sB0[tid] = b0[tid]; }
    for (int i = tid; i < NPOU * HH; i += 256) sbh[i] = bh[i];
    if (tid < NJ) sbl[tid] = bl[tid];
    __syncthreads();

    unsigned short* myA = &sA[wave * 4096];
    const int pbase = blockIdx.x * 256;

    {
        const int p = pbase + tid;
        float2 xv = ((const float2*)x)[p];
        float v[HH];
#pragma unroll
        for (int c = 0; c < HH; ++c)
            v[c] = fmaxf(fmaf(xv.x, sW0a[c], fmaf(xv.y, sW0b[c], sB0[c])), 0.0f);
#pragma unroll
        for (int c = 0; c < 8; ++c) {
            int4v r;
            r.x = (int)pk2(v[8 * c + 0], v[8 * c + 1]);
            r.y = (int)pk2(v[8 * c + 2], v[8 * c + 3]);
            r.z = (int)pk2(v[8 * c + 4], v[8 * c + 5]);
            r.w = (int)pk2(v[8 * c + 6], v[8 * c + 7]);
            *(int4v*)&myA[CHUNK_US(lane, c)] = r;
        }
    }

    float trunk[4][4][4];
#pragma unroll
    for (int mt = 0; mt < 4; ++mt)
#pragma unroll
        for (int nt = 0; nt < 4; ++nt)
#pragma unroll
            for (int q = 0; q < 4; ++q)
                trunk[mt][nt][q] = bf2f(myA[usIdx(mt * 16 + g * 4 + q, nt * 16 + r15)]);

#pragma unroll 1
    for (int r = 0; r < NPOU; ++r) {
        const unsigned short* wt = &sWhT[r * 4096];
        short8 bfr[2][4];
#pragma unroll
        for (int kc = 0; kc < 2; ++kc)
#pragma unroll
            for (int nt = 0; nt < 4; ++nt)
                bfr[kc][nt] = *(const short8*)&wt[CHUNK_US(nt * 16 + r15, kc * 4 + g)];
        float bias[4];
#pragma unroll
        for (int nt = 0; nt < 4; ++nt) bias[nt] = sbh[r * HH + nt * 16 + r15];

#pragma unroll
        for (int mt = 0; mt < 4; ++mt) {
            short8 a0 = *(const short8*)&myA[CHUNK_US(mt * 16 + r15, g)];
            short8 a1 = *(const short8*)&myA[CHUNK_US(mt * 16 + r15, 4 + g)];
            f32x4 acc[4];
#pragma unroll
            for (int nt = 0; nt < 4; ++nt) {
                acc[nt] = (f32x4)(0.0f);
                acc[nt] = __builtin_amdgcn_mfma_f32_16x16x32_bf16(a0, bfr[0][nt], acc[nt], 0, 0, 0);
                acc[nt] = __builtin_amdgcn_mfma_f32_16x16x32_bf16(a1, bfr[1][nt], acc[nt], 0, 0, 0);
            }
#pragma unroll
            for (int nt = 0; nt < 4; ++nt)
#pragma unroll
                for (int q = 0; q < 4; ++q) {
                    float t = trunk[mt][nt][q] + fmaxf(acc[nt][q] + bias[nt], 0.0f);
                    trunk[mt][nt][q] = t;
                    myA[usIdx(mt * 16 + g * 4 + q, nt * 16 + r15)] = rhu(t);
                }
        }
    }

    short8 bw0 = *(const short8*)&sWlT[CHUNK_US(r15, g)];
    short8 bw1 = *(const short8*)&sWlT[CHUNK_US(r15, 4 + g)];
    float lg[4][4], mx[4][4];
#pragma unroll
    for (int mt = 0; mt < 4; ++mt) {
        short8 a0 = *(const short8*)&myA[CHUNK_US(mt * 16 + r15, g)];
        short8 a1 = *(const short8*)&myA[CHUNK_US(mt * 16 + r15, 4 + g)];
        f32x4 acc = (f32x4)(0.0f);
        acc = __builtin_amdgcn_mfma_f32_16x16x32_bf16(a0, bw0, acc, 0, 0, 0);
        acc = __builtin_amdgcn_mfma_f32_16x16x32_bf16(a1, bw1, acc, 0, 0, 0);
#pragma unroll
        for (int q = 0; q < 4; ++q) { lg[mt][q] = acc[q] + sbl[r15]; mx[mt][q] = lg[mt][q]; }
    }
#pragma unroll
    for (int mask = 1; mask < 16; mask <<= 1)
#pragma unroll
        for (int mt = 0; mt < 4; ++mt)
#pragma unroll
            for (int q = 0; q < 4; ++q) mx[mt][q] = fmaxf(mx[mt][q], __shfl_xor(mx[mt][q], mask));
    float ev[4][4], sm[4][4];
#pragma unroll
    for (int mt = 0; mt < 4; ++mt)
#pragma unroll
        for (int q = 0; q < 4; ++q) { ev[mt][q] = __expf(lg[mt][q] - mx[mt][q]); sm[mt][q] = ev[mt][q]; }
#pragma unroll
    for (int mask = 1; mask < 16; mask <<= 1)
#pragma unroll
        for (int mt = 0; mt < 4; ++mt)
#pragma unroll
            for (int q = 0; q < 4; ++q) sm[mt][q] += __shfl_xor(sm[mt][q], mask);
#pragma unroll
    for (int mt = 0; mt < 4; ++mt)
#pragma unroll
        for (int q = 0; q < 4; ++q) {
            const int p = pbase + wave * 64 + mt * 16 + g * 4 + q;
            w_all[r15 * NP + p] = ev[mt][q] * __builtin_amdgcn_rcpf(sm[mt][q]);
        }
}

__global__ __launch_bounds__(256) void subnet_mfma_fallback(
    const float* __restrict__ x,
    const float* __restrict__ gW0, const float* __restrict__ gb0,
    const float* __restrict__ gWh, const float* __restrict__ gbh,
    const float* __restrict__ gWl, const float* __restrict__ gbl,
    const float* __restrict__ w_all,
    float* __restrict__ upart)
{
    __shared__ __align__(16) unsigned short sWt[NSUB * 64 * 64];
    __shared__ __align__(16) float sW0a[WID], sW0b[WID], sB0[WID];
    __shared__ __align__(16) float sbh[NSUB * WID];
    __shared__ __align__(16) float sWl[WID];
    __shared__ float sbl1v;

    const int tid  = threadIdx.x;
    const int j    = blockIdx.y;
    const int wave = tid >> 6;
    const int lane = tid & 63;
    const int c    = lane & 15;
    const int g    = lane >> 4;

    {
        const float* src = gWh + j * (NSUB * WID * WID);
        for (int idx = tid; idx < NSUB * WID * WID; idx += 256) {
            int L = idx >> 12, rem = idx & 4095;
            int k = rem >> 6, n = rem & 63;
            sWt[L * 4096 + usIdx(n, k)] = f2bf(L2E2 * src[idx]);
        }
        if (tid < WID) {
            float w0 = gW0[j * 2 * WID + tid], w1 = gW0[j * 2 * WID + WID + tid];
            sW0a[tid] = 2.0f * L2E2 * w0;
            sW0b[tid] = 2.0f * L2E2 * w1;
            sB0[tid]  = L2E2 * (gb0[j * WID + tid] - w0 - w1);
        }
        if (tid < NSUB * WID) sbh[tid] = L2E2 * gbh[j * NSUB * WID + tid];
        if (tid < WID) sWl[tid] = gWl[j * WID + tid];
        if (tid == 0) sbl1v = gbl[j];
    }
    __syncthreads();

    const int pb = blockIdx.x * 256 + wave * 64;

    short8 bf[2][4];
    {
        float xs0[4], xs1[4];
#pragma unroll
        for (int nt = 0; nt < 4; ++nt) {
            float2 xv = ((const float2*)x)[pb + nt * 16 + c];
            xs0[nt] = xv.x; xs1[nt] = xv.y;
        }
        f32x4 wa[2][2], wb[2][2], bb[2][2];
#pragma unroll
        for (int kc = 0; kc < 2; ++kc)
#pragma unroll
            for (int hf = 0; hf < 2; ++hf) {
                wa[kc][hf] = *(const f32x4*)&sW0a[kc * 32 + 8 * g + 4 * hf];
                wb[kc][hf] = *(const f32x4*)&sW0b[kc * 32 + 8 * g + 4 * hf];
                bb[kc][hf] = *(const f32x4*)&sB0 [kc * 32 + 8 * g + 4 * hf];
            }
        unsigned t[2][4][4];
#pragma unroll
        for (int kc = 0; kc < 2; ++kc)
#pragma unroll
            for (int pr = 0; pr < 4; ++pr) {
                const int h0 = pr >> 1, e0 = (2 * pr) & 3, e1 = e0 + 1;
#pragma unroll
                for (int nt = 0; nt < 4; ++nt) {
                    float v0 = tanh2(fmaf(xs0[nt], wa[kc][h0][e0], fmaf(xs1[nt], wb[kc][h0][e0], bb[kc][h0][e0])));
                    float v1 = tanh2(fmaf(xs0[nt], wa[kc][h0][e1], fmaf(xs1[nt], wb[kc][h0][e1], bb[kc][h0][e1])));
                    t[kc][nt][pr] = cvtpk(v0, v1);
                }
            }
#pragma unroll
        for (int kc = 0; kc < 2; ++kc)
#pragma unroll
            for (int nt = 0; nt < 4; ++nt)
                bf[kc][nt] = mk8(t[kc][nt][0], t[kc][nt][1], t[kc][nt][2], t[kc][nt][3]);
    }

    float red[4];
#pragma unroll
    for (int nt = 0; nt < 4; ++nt) red[nt] = 0.0f;

#pragma unroll
    for (int L = 0; L < NSUB; ++L) {
        const unsigned short* wt = &sWt[L * 4096];
        short8 aw[4][2];
#pragma unroll
        for (int mt = 0; mt < 4; ++mt)
#pragma unroll
            for (int kc = 0; kc < 2; ++kc)
                aw[mt][kc] = *(const short8*)&wt[CHUNK_US(mt * 16 + c, kc * 4 + g)];
        f32x4 bias[4];
#pragma unroll
        for (int mt = 0; mt < 4; ++mt)
            bias[mt] = *(const f32x4*)&sbh[L * 64 + mt * 16 + 4 * g];

#pragma unroll
        for (int nt = 0; nt < 4; ++nt) {
            f32x4 acc[4];
#pragma unroll
            for (int mt = 0; mt < 4; ++mt) acc[mt] = bias[mt];
#pragma unroll
            for (int mt = 0; mt < 4; ++mt) {
                acc[mt] = __builtin_amdgcn_mfma_f32_16x16x32_bf16(aw[mt][0], bf[0][nt], acc[mt], 0, 0, 0);
                acc[mt] = __builtin_amdgcn_mfma_f32_16x16x32_bf16(aw[mt][1], bf[1][nt], acc[mt], 0, 0, 0);
            }

            if (L < NSUB - 1) {
                float h[4][4];
#pragma unroll
                for (int mt = 0; mt < 4; ++mt)
#pragma unroll
                    for (int q = 0; q < 4; ++q) h[mt][q] = tanh2(acc[mt][q]);
                short8 btmp[2];
                CB_TRANSFORM(h, btmp);
                bf[0][nt] = btmp[0];
                bf[1][nt] = btmp[1];
            } else {
#pragma unroll
                for (int mt = 0; mt < 4; ++mt) {
                    f32x4 wlv = *(const f32x4*)&sWl[mt * 16 + 4 * g];
#pragma unroll
                    for (int q = 0; q < 4; ++q)
                        red[nt] = fmaf(tanh2(acc[mt][q]), wlv[q], red[nt]);
                }
            }
        }
    }

#pragma unroll
    for (int nt = 0; nt < 4; ++nt) {
        red[nt] += __shfl_xor(red[nt], 16);
        red[nt] += __shfl_xor(red[nt], 32);
    }
    float u = (g & 1) ? ((g & 2) ? red[3] : red[1]) : ((g & 2) ? red[2] : red[0]);
    u += sbl1v;

    const int p = pb + lane;
    upart[j * NP + p] = u * w_all[j * NP + p];
}

// ============ Reduce (fallback path only) ============
__global__ __launch_bounds__(256) void reduce_kernel(
    const float* __restrict__ x,
    const float* __restrict__ upart,
    float* __restrict__ out)
{
    const int p = blockIdx.x * 256 + threadIdx.x;
    float s = 0.0f;
#pragma unroll
    for (int j = 0; j < NJ; ++j) s += upart[j * NP + p];
    float2 xv = ((const float2*)x)[p];
    float s0 = __builtin_amdgcn_sinf(xv.x * 0.5f);
    float s1 = __builtin_amdgcn_sinf(xv.y * 0.5f);
    out[p] = s * s0 * s1;
}

extern "C" void kernel_launch(void* const* d_in, const int* in_sizes, int n_in,
                              void* d_out, int out_size, void* d_ws, size_t ws_size,
                              hipStream_t stream) {
    const float* x      = (const float*)d_in[0];
    const float* sub_W0 = (const float*)d_in[1];
    const float* sub_b0 = (const float*)d_in[2];
    const float* sub_Wh = (const float*)d_in[3];
    const float* sub_bh = (const float*)d_in[4];
    const float* sub_Wl = (const float*)d_in[5];
    const float* sub_bl = (const float*)d_in[6];
    const float* pou_W0 = (const float*)d_in[7];
    const float* pou_b0 = (const float*)d_in[8];
    const float* pou_Wh = (const float*)d_in[9];
    const float* pou_bh = (const float*)d_in[10];
    const float* pou_Wl = (const float*)d_in[11];
    const float* pou_bl = (const float*)d_in[12];

    float* w_all = (float*)d_ws;                   // [J][P] 4 MB
    float* upart = (float*)d_ws + (size_t)NJ * NP; // [J][P] 4 MB (fallback only)
    char*  extra  = (char*)d_ws + (size_t)2 * NJ * NP * 4;
    void*  swf    = (void*)extra;                               // 256 KB subnet Wh frags
    float* sprm   = (float*)(extra + (size_t)NJ * 1024 * 16);   // 32 KB subnet params
    char*  extra2 = extra + (size_t)NJ * 1024 * 16 + (size_t)NJ * 512 * 4;
    void*  pwf    = (void*)extra2;                              // 34816 B pou frags
    float* pprm   = (float*)(extra2 + 2176 * 16);               // 2 KB pou params
    void*  swf0   = (void*)(extra2 + 2176 * 16 + 512 * 4);      // 64 KB subnet L0 frags

    const size_t need = (size_t)2 * NJ * NP * 4 + (size_t)NJ * 1024 * 16
                      + (size_t)NJ * 512 * 4 + 2176 * 16 + 512 * 4
                      + (size_t)NJ * 256 * 16;
    const bool use_prep = (ws_size >= need);

    if (use_prep) {
        prep_all_kernel<<<89, 256, 0, stream>>>(sub_W0, sub_b0, sub_Wh, sub_bh, sub_Wl, sub_bl,
                                                pou_W0, pou_b0, pou_Wh, pou_bh, pou_Wl, pou_bl,
                                                (int4v*)swf, sprm, (int4v*)pwf, pprm,
                                                (int4v*)swf0);
        pou16_kernel<<<NP / 64, 256, 0, stream>>>(x, (const short8*)pwf, pprm, w_all,
                                                  (float*)d_out);
        dim3 g2(NP / 256, NJ);
        subnet_nolds_kernel<<<g2, 256, 0, stream>>>(x, (const short8*)swf, (const short8*)swf0,
                                                    sprm, w_all, (float*)d_out);
    } else {
        pou_mfma_kernel<<<NP / 256, 256, 0, stream>>>(x, pou_W0, pou_b0, pou_Wh, pou_bh,
                                                      pou_Wl, pou_bl, w_all);
        dim3 g2(NP / 256, NJ);
        subnet_mfma_fallback<<<g2, 256, 0, stream>>>(x, sub_W0, sub_b0, sub_Wh, sub_bh,
                                                     sub_Wl, sub_bl, w_all, upart);
        reduce_kernel<<<NP / 256, 256, 0, stream>>>(x, upart, (float*)d_out);
    }
}